// Round 4
// baseline (1942.433 us; speedup 1.0000x reference)
//
#include <hip/hip_runtime.h>

// GuidedAttention on MI355X, round 4: resubmission of round 3 (two straight
// infra failures on a dead container — code never ran). Algorithm unchanged.
// b=8, n=1024, c=512, H=8, hd=64.
// ws (bf16 elems): Q[4M] K[4M] V[4M] Z[4M] S[64M]  = 160 MB total (+guard).
// Pipeline: k_qkv -> k_qk (S bf16) -> k_csa (conv+bn+sigmoid+softmax+AV fused)
//           -> k_proj (+bias+residual).

#define DINL __device__ __forceinline__
typedef unsigned short u16;
typedef unsigned int u32;

DINL u16 f2bf(float f) {
  u32 u = __float_as_uint(f);
  u += 0x7fffu + ((u >> 16) & 1u);
  return (u16)(u >> 16);
}
DINL float bf2f(u16 h) { return __uint_as_float(((u32)h) << 16); }
DINL float bflo(u32 u) { return __uint_as_float(u << 16); }
DINL float bfhi(u32 u) { return __uint_as_float(u & 0xffff0000u); }

// ---------- Kernel 1: QKV projection. M=8192, N=1536, K=512, out bf16 ----------
__global__ __launch_bounds__(256) void k_qkv(const float* __restrict__ x,
                                             const float* __restrict__ w,
                                             u16* __restrict__ Q,
                                             u16* __restrict__ K,
                                             u16* __restrict__ V) {
  __shared__ float sAt[32][68];  // [k][m], padded
  __shared__ float sBt[32][68];  // [k][n], padded
  const int tid = threadIdx.x;
  const int m0 = blockIdx.x * 64, n0 = blockIdx.y * 64;
  const int ty = tid >> 4, tx = tid & 15;
  float acc[4][4] = {};
  for (int k0 = 0; k0 < 512; k0 += 32) {
    __syncthreads();
    for (int u = tid; u < 512; u += 256) {
      int row = u >> 3, q = u & 7;
      float4 va = *(const float4*)&x[(size_t)(m0 + row) * 512 + k0 + q * 4];
      sAt[q * 4 + 0][row] = va.x; sAt[q * 4 + 1][row] = va.y;
      sAt[q * 4 + 2][row] = va.z; sAt[q * 4 + 3][row] = va.w;
      float4 vb = *(const float4*)&w[(size_t)(n0 + row) * 512 + k0 + q * 4];
      sBt[q * 4 + 0][row] = vb.x; sBt[q * 4 + 1][row] = vb.y;
      sBt[q * 4 + 2][row] = vb.z; sBt[q * 4 + 3][row] = vb.w;
    }
    __syncthreads();
#pragma unroll
    for (int k = 0; k < 32; ++k) {
      float4 a4 = *(const float4*)&sAt[k][ty * 4];
      float4 b4 = *(const float4*)&sBt[k][tx * 4];
      float a[4] = {a4.x, a4.y, a4.z, a4.w};
      float b[4] = {b4.x, b4.y, b4.z, b4.w};
#pragma unroll
      for (int i = 0; i < 4; ++i)
#pragma unroll
        for (int j = 0; j < 4; ++j) acc[i][j] += a[i] * b[j];
    }
  }
  const int nn0 = n0 + tx * 4;
  const int which = nn0 >> 9;
  const int co = nn0 & 511;
  const int head = co >> 6, d = co & 63;
  u16* dst = (which == 0) ? Q : (which == 1) ? K : V;
  const float sc = (which == 0) ? 0.125f : 1.f;
#pragma unroll
  for (int i = 0; i < 4; ++i) {
    int m = m0 + ty * 4 + i;
    int bb = m >> 10, ii = m & 1023;
    size_t idx = ((((size_t)bb * 8 + head) << 10) + ii) * 64 + d;
    u32 lo = (u32)f2bf(acc[i][0] * sc) | ((u32)f2bf(acc[i][1] * sc) << 16);
    u32 hi = (u32)f2bf(acc[i][2] * sc) | ((u32)f2bf(acc[i][3] * sc) << 16);
    *(uint2*)&dst[idx] = make_uint2(lo, hi);
  }
}

// ---------- Kernel 2: S = Q @ K^T per (b,h). 1024x1024x64, bf16 in/out ----------
__global__ __launch_bounds__(256) void k_qk(const u16* __restrict__ Q,
                                            const u16* __restrict__ Kp,
                                            u16* __restrict__ S) {
  const int bh = blockIdx.z;
  const u16* Qb = Q + (size_t)bh * 65536;
  const u16* Kb = Kp + (size_t)bh * 65536;
  u16* Sb = S + (size_t)bh * 1048576;
  __shared__ u16 sAt[64][72];  // [d][m], padded
  __shared__ u16 sBt[64][72];  // [d][n], padded
  const int tid = threadIdx.x;
  const int m0 = blockIdx.x * 64, n0 = blockIdx.y * 64;
  for (int u = tid; u < 512; u += 256) {
    int row = u >> 3, q = u & 7;
    uint4 va = *(const uint4*)&Qb[(m0 + row) * 64 + q * 8];
    sAt[q * 8 + 0][row] = (u16)va.x; sAt[q * 8 + 1][row] = (u16)(va.x >> 16);
    sAt[q * 8 + 2][row] = (u16)va.y; sAt[q * 8 + 3][row] = (u16)(va.y >> 16);
    sAt[q * 8 + 4][row] = (u16)va.z; sAt[q * 8 + 5][row] = (u16)(va.z >> 16);
    sAt[q * 8 + 6][row] = (u16)va.w; sAt[q * 8 + 7][row] = (u16)(va.w >> 16);
    uint4 vb = *(const uint4*)&Kb[(n0 + row) * 64 + q * 8];
    sBt[q * 8 + 0][row] = (u16)vb.x; sBt[q * 8 + 1][row] = (u16)(vb.x >> 16);
    sBt[q * 8 + 2][row] = (u16)vb.y; sBt[q * 8 + 3][row] = (u16)(vb.y >> 16);
    sBt[q * 8 + 4][row] = (u16)vb.z; sBt[q * 8 + 5][row] = (u16)(vb.z >> 16);
    sBt[q * 8 + 6][row] = (u16)vb.w; sBt[q * 8 + 7][row] = (u16)(vb.w >> 16);
  }
  __syncthreads();
  const int ty = tid >> 4, tx = tid & 15;
  float acc[4][4] = {};
#pragma unroll 4
  for (int k = 0; k < 64; ++k) {
    uint2 ua = *(const uint2*)&sAt[k][ty * 4];
    uint2 ub = *(const uint2*)&sBt[k][tx * 4];
    float a[4] = {bflo(ua.x), bfhi(ua.x), bflo(ua.y), bfhi(ua.y)};
    float b[4] = {bflo(ub.x), bfhi(ub.x), bflo(ub.y), bfhi(ub.y)};
#pragma unroll
    for (int i = 0; i < 4; ++i)
#pragma unroll
      for (int j = 0; j < 4; ++j) acc[i][j] += a[i] * b[j];
  }
#pragma unroll
  for (int i = 0; i < 4; ++i) {
    int m = m0 + ty * 4 + i;
    u32 lo = (u32)f2bf(acc[i][0]) | ((u32)f2bf(acc[i][1]) << 16);
    u32 hi = (u32)f2bf(acc[i][2]) | ((u32)f2bf(acc[i][3]) << 16);
    *(uint2*)&Sb[(size_t)m * 1024 + n0 + tx * 4] = make_uint2(lo, hi);
  }
}

// ---------- Kernel 3: conv3x3 + BN + sigmoid + softmax + AV, fused ----------
// Block per (b, 2 rows). LDS: S rows i0-1..i0+2 (64KB, reused as V tiles),
// P=exp(sigmoid(...)) (32KB), weights, denominators.
__global__ __launch_bounds__(256) void k_csa(
    const u16* __restrict__ S, const u16* __restrict__ V,
    const float* __restrict__ cw, const float* __restrict__ cb,
    const float* __restrict__ bg, const float* __restrict__ bb,
    const float* __restrict__ bm, const float* __restrict__ bv,
    u16* __restrict__ Z) {
  const int b = blockIdx.x >> 9;
  const int i0 = (blockIdx.x & 511) * 2;
  __shared__ u16 sIn[32768];  // [rr4][h8][1024]; reused as V [h8][j64][d64]
  __shared__ u16 sP[16384];   // [r2][oh8][1024]
  __shared__ float sW[576];
  __shared__ float sDen[16];
  const int tid = threadIdx.x;
  for (int u = tid; u < 576; u += 256) sW[u] = cw[u];
  if (tid < 16) sDen[tid] = 0.f;
  for (int u = tid; u < 4096; u += 256) {
    int rr = u >> 10, rem = u & 1023, h = rem >> 7, q = rem & 127;
    int rrow = i0 - 1 + rr;
    uint4 val = make_uint4(0u, 0u, 0u, 0u);
    if (rrow >= 0 && rrow < 1024)
      val = *(const uint4*)&S[((((size_t)b * 8 + h) << 10) + rrow) * 1024 + q * 8];
    *(uint4*)&sIn[((rr * 8 + h) << 10) + q * 8] = val;
  }
  __syncthreads();
  // conv: thread -> (r = tid>>7, 8 cols at jseg*8), all 8 out-heads in regs
  const int r = tid >> 7, jseg = tid & 127;
  float acc[8][8];
#pragma unroll
  for (int i = 0; i < 8; ++i)
#pragma unroll
    for (int j = 0; j < 8; ++j) acc[i][j] = 0.f;
  for (int ih = 0; ih < 8; ++ih) {
#pragma unroll
    for (int dr = 0; dr < 3; ++dr) {
      const u16* rb = &sIn[(((r + dr) * 8 + ih) << 10)];
      uint4 m4 = *(const uint4*)&rb[jseg * 8];
      u32 lft = (jseg > 0) ? *(const u32*)&rb[jseg * 8 - 2] : 0u;
      u32 rgt = (jseg < 127) ? *(const u32*)&rb[jseg * 8 + 8] : 0u;
      float s[10];
      s[0] = bfhi(lft);
      s[1] = bflo(m4.x); s[2] = bfhi(m4.x);
      s[3] = bflo(m4.y); s[4] = bfhi(m4.y);
      s[5] = bflo(m4.z); s[6] = bfhi(m4.z);
      s[7] = bflo(m4.w); s[8] = bfhi(m4.w);
      s[9] = bflo(rgt);
#pragma unroll
      for (int oh = 0; oh < 8; ++oh) {
        const float* wp = &sW[((oh * 8 + ih) * 3 + dr) * 3];
        float w0 = wp[0], w1 = wp[1], w2 = wp[2];
#pragma unroll
        for (int kk = 0; kk < 8; ++kk)
          acc[oh][kk] += w0 * s[kk] + w1 * s[kk + 1] + w2 * s[kk + 2];
      }
    }
  }
#pragma unroll
  for (int oh = 0; oh < 8; ++oh) {
    float ah = bg[oh] * rsqrtf(bv[oh] + 1e-5f);
    float bh = bb[oh] - bm[oh] * ah;
    float bias = cb[oh];
    float psum = 0.f;
    u32 pk[4];
#pragma unroll
    for (int e = 0; e < 4; ++e) {
      u32 w2 = 0u;
#pragma unroll
      for (int o = 0; o < 2; ++o) {
        float t = (acc[oh][e * 2 + o] + bias) * ah + bh;
        float p = 1.f / (1.f + __expf(-t));
        float ex = __expf(p);  // softmax numerator (no max needed: p in (0,1))
        psum += ex;
        w2 |= (u32)f2bf(ex) << (o * 16);
      }
      pk[e] = w2;
    }
    *(uint4*)&sP[((r * 8 + oh) << 10) + jseg * 8] = make_uint4(pk[0], pk[1], pk[2], pk[3]);
    atomicAdd(&sDen[r * 8 + oh], psum);
  }
  // AV: thread -> (h = tid>>5, 2 d at d0), accumulate over all 1024 j
  const int h = tid >> 5, d0 = (tid & 31) * 2;
  float n00 = 0.f, n01 = 0.f, n10 = 0.f, n11 = 0.f;
  for (int jt = 0; jt < 16; ++jt) {
    __syncthreads();
    for (int u = tid; u < 4096; u += 256) {
      int hh = u >> 9, rem = u & 511, jj = rem >> 3, q = rem & 7;
      uint4 val = *(const uint4*)&V[((((size_t)b * 8 + hh) << 10) + jt * 64 + jj) * 64 + q * 8];
      *(uint4*)&sIn[((hh * 64 + jj) << 6) + q * 8] = val;
    }
    __syncthreads();
#pragma unroll 8
    for (int jj = 0; jj < 64; ++jj) {
      int j = jt * 64 + jj;
      float a0 = bf2f(sP[(h << 10) + j]);
      float a1 = bf2f(sP[((8 + h) << 10) + j]);
      u32 vv = *(const u32*)&sIn[((h * 64 + jj) << 6) + d0];
      float v0 = bflo(vv), v1 = bfhi(vv);
      n00 += a0 * v0; n01 += a0 * v1;
      n10 += a1 * v0; n11 += a1 * v1;
    }
  }
  float di0 = 1.f / sDen[h];
  float di1 = 1.f / sDen[8 + h];
  size_t zo = (((size_t)b << 10) + i0) * 512 + h * 64 + d0;
  *(u32*)&Z[zo] = (u32)f2bf(n00 * di0) | ((u32)f2bf(n01 * di0) << 16);
  *(u32*)&Z[zo + 512] = (u32)f2bf(n10 * di1) | ((u32)f2bf(n11 * di1) << 16);
}

// ---------- Kernel 4: out = Z @ W^T + b + x. M=8192, N=512, K=512 ----------
__global__ __launch_bounds__(256) void k_proj(const u16* __restrict__ Z,
                                              const float* __restrict__ w,
                                              const float* __restrict__ bias,
                                              const float* __restrict__ xin,
                                              float* __restrict__ out) {
  __shared__ u16 sAt[32][72];    // [k][m] bf16, padded
  __shared__ float sBt[32][68];  // [k][n] fp32, padded
  const int tid = threadIdx.x;
  const int m0 = blockIdx.x * 64, n0 = blockIdx.y * 64;
  const int ty = tid >> 4, tx = tid & 15;
  float acc[4][4] = {};
  for (int k0 = 0; k0 < 512; k0 += 32) {
    __syncthreads();
    for (int u = tid; u < 256; u += 256) {
      int row = u >> 2, q = u & 3;
      uint4 za = *(const uint4*)&Z[(size_t)(m0 + row) * 512 + k0 + q * 8];
      sAt[q * 8 + 0][row] = (u16)za.x; sAt[q * 8 + 1][row] = (u16)(za.x >> 16);
      sAt[q * 8 + 2][row] = (u16)za.y; sAt[q * 8 + 3][row] = (u16)(za.y >> 16);
      sAt[q * 8 + 4][row] = (u16)za.z; sAt[q * 8 + 5][row] = (u16)(za.z >> 16);
      sAt[q * 8 + 6][row] = (u16)za.w; sAt[q * 8 + 7][row] = (u16)(za.w >> 16);
    }
    for (int u = tid; u < 512; u += 256) {
      int row = u >> 3, q = u & 7;
      float4 vb = *(const float4*)&w[(size_t)(n0 + row) * 512 + k0 + q * 4];
      sBt[q * 4 + 0][row] = vb.x; sBt[q * 4 + 1][row] = vb.y;
      sBt[q * 4 + 2][row] = vb.z; sBt[q * 4 + 3][row] = vb.w;
    }
    __syncthreads();
#pragma unroll
    for (int k = 0; k < 32; ++k) {
      uint2 ua = *(const uint2*)&sAt[k][ty * 4];
      float4 b4 = *(const float4*)&sBt[k][tx * 4];
      float a[4] = {bflo(ua.x), bfhi(ua.x), bflo(ua.y), bfhi(ua.y)};
      float b[4] = {b4.x, b4.y, b4.z, b4.w};
#pragma unroll
      for (int i = 0; i < 4; ++i)
#pragma unroll
        for (int j = 0; j < 4; ++j) acc[i][j] += a[i] * b[j];
    }
  }
#pragma unroll
  for (int i = 0; i < 4; ++i) {
    int m = m0 + ty * 4 + i;
    int nn = n0 + tx * 4;
    size_t o = (size_t)m * 512 + nn;
    float4 rres = *(const float4*)&xin[o];
    *(float4*)&out[o] = make_float4(acc[i][0] + bias[nn + 0] + rres.x,
                                    acc[i][1] + bias[nn + 1] + rres.y,
                                    acc[i][2] + bias[nn + 2] + rres.z,
                                    acc[i][3] + bias[nn + 3] + rres.w);
  }
}

extern "C" void kernel_launch(void* const* d_in, const int* in_sizes, int n_in,
                              void* d_out, int out_size, void* d_ws, size_t ws_size,
                              hipStream_t stream) {
  // ws requirement: Q,K,V,Z bf16 (4 x 4,194,304 elems) + S bf16 (67,108,864
  // elems) = 167,772,160 bytes. If the harness gives us less, launch nothing:
  // the validation will fail cleanly on poisoned d_out (absmax ~ 4e2) instead
  // of faulting the GPU.
  const size_t need = (16777216ull + 67108864ull) * sizeof(u16);
  if (ws_size < need) return;

  const float* x      = (const float*)d_in[0];
  const float* qkv_w  = (const float*)d_in[1];
  const float* proj_w = (const float*)d_in[2];
  const float* proj_b = (const float*)d_in[3];
  const float* conv_w = (const float*)d_in[4];
  const float* conv_b = (const float*)d_in[5];
  const float* bn_g   = (const float*)d_in[6];
  const float* bn_b   = (const float*)d_in[7];
  const float* bn_m   = (const float*)d_in[8];
  const float* bn_v   = (const float*)d_in[9];
  float* out = (float*)d_out;

  u16* Wq = (u16*)d_ws;
  u16* Wk = Wq + 4194304;
  u16* Wv = Wq + 8388608;
  u16* Wz = Wq + 12582912;
  u16* Ws = Wq + 16777216;  // 64M elems

  k_qkv<<<dim3(128, 24), 256, 0, stream>>>(x, qkv_w, Wq, Wk, Wv);
  k_qk<<<dim3(16, 16, 64), 256, 0, stream>>>(Wq, Wk, Ws);
  k_csa<<<dim3(4096), 256, 0, stream>>>(Ws, Wv, conv_w, conv_b, bn_g, bn_b,
                                        bn_m, bn_v, Wz);
  k_proj<<<dim3(128, 8), 256, 0, stream>>>(Wz, proj_w, proj_b, x, out);
}

// Round 5
// 636.484 us; speedup vs baseline: 3.0518x; 3.0518x over previous
//
#include <hip/hip_runtime.h>

// GuidedAttention on MI355X, round 5.
// b=8, n=1024, c=512, H=8, hd=64.
// ws layout (160 MB): [Q bf16 8MB | D f32 256KB overlaid after k_qk]
//                     [K bf16 8MB][V bf16 8MB][Z bf16 8MB]
//                     [S fp8 64MB][P fp8 64MB]
// Pipeline: k_qkv (fp32 VALU) -> k_qk (bf16 MFMA -> S fp8)
//        -> k_conv (conv+bn+sigmoid+exp -> P fp8, D f32)
//        -> k_av (fp8 MFMA, /D -> Z bf16) -> k_proj (fp32 VALU + residual).

#define DINL __device__ __forceinline__
typedef unsigned short u16;
typedef unsigned int u32;
typedef unsigned long long u64;
typedef short bf16x8 __attribute__((ext_vector_type(8)));
typedef float f32x4 __attribute__((ext_vector_type(4)));
typedef float f32x2 __attribute__((ext_vector_type(2)));

DINL u16 f2bf(float f) {
  u32 u = __float_as_uint(f);
  u += 0x7fffu + ((u >> 16) & 1u);
  return (u16)(u >> 16);
}
DINL float bf2f(u16 h) { return __uint_as_float(((u32)h) << 16); }
DINL float bflo(u32 u) { return __uint_as_float(u << 16); }
DINL float bfhi(u32 u) { return __uint_as_float(u & 0xffff0000u); }

DINL u32 pk4_fp8(float a, float b, float c, float d) {
  u32 r = 0;
  r = (u32)__builtin_amdgcn_cvt_pk_fp8_f32(a, b, (int)r, false);
  r = (u32)__builtin_amdgcn_cvt_pk_fp8_f32(c, d, (int)r, true);
  return r;
}
DINL f32x2 up2_lo(u32 w) { return __builtin_amdgcn_cvt_pk_f32_fp8((int)w, false); }
DINL f32x2 up2_hi(u32 w) { return __builtin_amdgcn_cvt_pk_f32_fp8((int)w, true); }
DINL unsigned char f2fp8(float v) {
  return (unsigned char)((u32)__builtin_amdgcn_cvt_pk_fp8_f32(v, v, 0, false) & 0xffu);
}

// ---------- Kernel 1: QKV projection. M=8192, N=1536, K=512, out bf16 ----------
__global__ __launch_bounds__(256) void k_qkv(const float* __restrict__ x,
                                             const float* __restrict__ w,
                                             u16* __restrict__ Q,
                                             u16* __restrict__ K,
                                             u16* __restrict__ V) {
  __shared__ float sAt[32][68];
  __shared__ float sBt[32][68];
  const int tid = threadIdx.x;
  const int m0 = blockIdx.x * 64, n0 = blockIdx.y * 64;
  const int ty = tid >> 4, tx = tid & 15;
  float acc[4][4] = {};
  for (int k0 = 0; k0 < 512; k0 += 32) {
    __syncthreads();
    for (int u = tid; u < 512; u += 256) {
      int row = u >> 3, q = u & 7;
      float4 va = *(const float4*)&x[(size_t)(m0 + row) * 512 + k0 + q * 4];
      sAt[q * 4 + 0][row] = va.x; sAt[q * 4 + 1][row] = va.y;
      sAt[q * 4 + 2][row] = va.z; sAt[q * 4 + 3][row] = va.w;
      float4 vb = *(const float4*)&w[(size_t)(n0 + row) * 512 + k0 + q * 4];
      sBt[q * 4 + 0][row] = vb.x; sBt[q * 4 + 1][row] = vb.y;
      sBt[q * 4 + 2][row] = vb.z; sBt[q * 4 + 3][row] = vb.w;
    }
    __syncthreads();
#pragma unroll
    for (int k = 0; k < 32; ++k) {
      float4 a4 = *(const float4*)&sAt[k][ty * 4];
      float4 b4 = *(const float4*)&sBt[k][tx * 4];
      float a[4] = {a4.x, a4.y, a4.z, a4.w};
      float b[4] = {b4.x, b4.y, b4.z, b4.w};
#pragma unroll
      for (int i = 0; i < 4; ++i)
#pragma unroll
        for (int j = 0; j < 4; ++j) acc[i][j] += a[i] * b[j];
    }
  }
  const int nn0 = n0 + tx * 4;
  const int which = nn0 >> 9;
  const int co = nn0 & 511;
  const int head = co >> 6, d = co & 63;
  u16* dst = (which == 0) ? Q : (which == 1) ? K : V;
  const float sc = (which == 0) ? 0.125f : 1.f;
#pragma unroll
  for (int i = 0; i < 4; ++i) {
    int m = m0 + ty * 4 + i;
    int bb = m >> 10, ii = m & 1023;
    size_t idx = ((((size_t)bb * 8 + head) << 10) + ii) * 64 + d;
    u32 lo = (u32)f2bf(acc[i][0] * sc) | ((u32)f2bf(acc[i][1] * sc) << 16);
    u32 hi = (u32)f2bf(acc[i][2] * sc) | ((u32)f2bf(acc[i][3] * sc) << 16);
    *(uint2*)&dst[idx] = make_uint2(lo, hi);
  }
}

// ---------- Kernel 2: S = Q @ K^T per (b,h), bf16 MFMA, out fp8 ----------
// 128x128 tile, K=64 single pass. 4 waves in 2x2.
__global__ __launch_bounds__(256) void k_qk(const u16* __restrict__ Q,
                                            const u16* __restrict__ Kp,
                                            unsigned char* __restrict__ S8) {
  const int bh = blockIdx.z;
  const u16* Qb = Q + (size_t)bh * 65536;
  const u16* Kb = Kp + (size_t)bh * 65536;
  __shared__ __align__(16) u16 sQ[128 * 64];
  __shared__ __align__(16) u16 sK[128 * 64];
  const int tid = threadIdx.x;
  const int m0 = blockIdx.x * 128, n0 = blockIdx.y * 128;
  {
    int row = tid >> 1, half = tid & 1;
    const u16* gq = &Qb[(size_t)(m0 + row) * 64 + half * 32];
    const u16* gk = &Kb[(size_t)(n0 + row) * 64 + half * 32];
    int xr = row & 7;
#pragma unroll
    for (int q = 0; q < 4; ++q) {
      int gp = (half * 4 + q) ^ xr;
      *(uint4*)&sQ[row * 64 + gp * 8] = *(const uint4*)&gq[q * 8];
      *(uint4*)&sK[row * 64 + gp * 8] = *(const uint4*)&gk[q * 8];
    }
  }
  __syncthreads();
  const int lane = tid & 63, wid = tid >> 6;
  const int wr = wid >> 1, wc = wid & 1;
  const int l15 = lane & 15, l4 = lane >> 4;
  f32x4 acc[4][4] = {};
  bf16x8 af[4][2], bf[4][2];
#pragma unroll
  for (int mr = 0; mr < 4; ++mr) {
    int row = wr * 64 + mr * 16 + l15;
#pragma unroll
    for (int ks = 0; ks < 2; ++ks)
      af[mr][ks] = *(bf16x8*)&sQ[row * 64 + ((ks * 4 + l4) ^ (row & 7)) * 8];
  }
#pragma unroll
  for (int nr = 0; nr < 4; ++nr) {
    int row = wc * 64 + nr * 16 + l15;
#pragma unroll
    for (int ks = 0; ks < 2; ++ks)
      bf[nr][ks] = *(bf16x8*)&sK[row * 64 + ((ks * 4 + l4) ^ (row & 7)) * 8];
  }
#pragma unroll
  for (int mr = 0; mr < 4; ++mr)
#pragma unroll
    for (int nr = 0; nr < 4; ++nr)
#pragma unroll
      for (int ks = 0; ks < 2; ++ks)
        acc[mr][nr] = __builtin_amdgcn_mfma_f32_16x16x32_bf16(af[mr][ks], bf[nr][ks],
                                                              acc[mr][nr], 0, 0, 0);
  __syncthreads();
  unsigned char* t8 = (unsigned char*)sQ;  // reuse 16KB as fp8 [128][128]
#pragma unroll
  for (int mr = 0; mr < 4; ++mr) {
    int mloc = wr * 64 + mr * 16 + l4 * 4;
#pragma unroll
    for (int nr = 0; nr < 4; ++nr) {
      int nloc = wc * 64 + nr * 16 + l15;
#pragma unroll
      for (int r = 0; r < 4; ++r)
        t8[(mloc + r) * 128 + nloc] = f2fp8(acc[mr][nr][r]);
    }
  }
  __syncthreads();
  {
    int row = tid >> 1, c0 = (tid & 1) * 64;
    unsigned char* dst = &S8[((size_t)bh << 20) + (size_t)(m0 + row) * 1024 + n0 + c0];
#pragma unroll
    for (int q = 0; q < 4; ++q)
      *(uint4*)&dst[q * 16] = *(uint4*)&t8[row * 128 + c0 + q * 16];
  }
}

// ---------- Kernel 3: conv3x3(heads) + BN + sigmoid + exp -> P fp8, D f32 ----------
// Block per (b, row i). LDS: 24 rows (8 ih x 3 dr) x 1024 bf16 = 48KB.
__global__ __launch_bounds__(256) void k_conv(
    const unsigned char* __restrict__ S8, unsigned char* __restrict__ P8,
    float* __restrict__ D, const float* __restrict__ cw,
    const float* __restrict__ cb, const float* __restrict__ bg,
    const float* __restrict__ bb, const float* __restrict__ bm,
    const float* __restrict__ bv) {
  const int b = blockIdx.x >> 10, i = blockIdx.x & 1023;
  __shared__ __align__(16) u16 sS[24 * 1024];
  __shared__ float sW[576];
  const int tid = threadIdx.x;
  for (int u = tid; u < 576; u += 256) sW[u] = cw[u];
#pragma unroll
  for (int it = 0; it < 3; ++it) {
    int g = it * 8 + (tid >> 5);
    int col0 = (tid & 31) * 32;
    int ih = g / 3, dr = g - ih * 3;
    int srow = i - 1 + dr;
    uint4 v0 = make_uint4(0, 0, 0, 0), v1 = make_uint4(0, 0, 0, 0);
    if (srow >= 0 && srow < 1024) {
      const unsigned char* src =
          &S8[((size_t)(b * 8 + ih) << 20) + (size_t)srow * 1024 + col0];
      v0 = *(const uint4*)src;
      v1 = *(const uint4*)(src + 16);
    }
    u32 in[8] = {v0.x, v0.y, v0.z, v0.w, v1.x, v1.y, v1.z, v1.w};
    u32 outw[16];
#pragma unroll
    for (int t = 0; t < 8; ++t) {
      f32x2 lo = up2_lo(in[t]), hi = up2_hi(in[t]);
      outw[t * 2] = (u32)f2bf(lo.x) | ((u32)f2bf(lo.y) << 16);
      outw[t * 2 + 1] = (u32)f2bf(hi.x) | ((u32)f2bf(hi.y) << 16);
    }
    u16* dst = &sS[g * 1024 + col0];
#pragma unroll
    for (int q = 0; q < 4; ++q)
      *(uint4*)&dst[q * 8] =
          make_uint4(outw[q * 4], outw[q * 4 + 1], outw[q * 4 + 2], outw[q * 4 + 3]);
  }
  __syncthreads();
  const int oh = tid >> 5, jseg = tid & 31, j0 = jseg * 32;
  float av[32];
#pragma unroll
  for (int kk = 0; kk < 32; ++kk) av[kk] = 0.f;
  for (int ih = 0; ih < 8; ++ih) {
#pragma unroll
    for (int dr = 0; dr < 3; ++dr) {
      const u16* rb = &sS[(ih * 3 + dr) * 1024];
      const float* wp = &sW[((oh * 8 + ih) * 3 + dr) * 3];
      float w0 = wp[0], w1 = wp[1], w2 = wp[2];
      uint4 q0 = *(const uint4*)&rb[j0];
      uint4 q1 = *(const uint4*)&rb[j0 + 8];
      uint4 q2 = *(const uint4*)&rb[j0 + 16];
      uint4 q3 = *(const uint4*)&rb[j0 + 24];
      u32 lft = (jseg > 0) ? *(const u32*)&rb[j0 - 2] : 0u;
      u32 rgt = (jseg < 31) ? *(const u32*)&rb[j0 + 32] : 0u;
      float s[34];
      s[0] = bfhi(lft);
      u32 mm[8] = {q0.x, q0.y, q0.z, q0.w, q1.x, q1.y, q1.z, q1.w};
      u32 nn[8] = {q2.x, q2.y, q2.z, q2.w, q3.x, q3.y, q3.z, q3.w};
#pragma unroll
      for (int t = 0; t < 8; ++t) {
        s[1 + t * 2] = bflo(mm[t]); s[2 + t * 2] = bfhi(mm[t]);
        s[17 + t * 2] = bflo(nn[t]); s[18 + t * 2] = bfhi(nn[t]);
      }
      s[33] = bflo(rgt);
#pragma unroll
      for (int kk = 0; kk < 32; ++kk)
        av[kk] += w0 * s[kk] + w1 * s[kk + 1] + w2 * s[kk + 2];
    }
  }
  const float ah = bg[oh] * rsqrtf(bv[oh] + 1e-5f);
  const float bh2 = bb[oh] - bm[oh] * ah;
  const float bias = cb[oh];
  u32 pw[8];
  float psum = 0.f;
#pragma unroll
  for (int e = 0; e < 8; ++e) {
    float f[4];
#pragma unroll
    for (int o = 0; o < 4; ++o) {
      float t = (av[e * 4 + o] + bias) * ah + bh2;
      float p = 1.f / (1.f + __expf(-t));
      f[o] = __expf(p);  // softmax numerator; p in (0,1) so no max needed
    }
    pw[e] = pk4_fp8(f[0], f[1], f[2], f[3]);
    // denominator from the QUANTIZED numerators for exact normalization
    f32x2 lo = up2_lo(pw[e]), hi = up2_hi(pw[e]);
    psum += (lo.x + lo.y) + (hi.x + hi.y);
  }
  unsigned char* dst = &P8[((size_t)(b * 8 + oh) << 20) + (size_t)i * 1024 + j0];
  *(uint4*)&dst[0] = make_uint4(pw[0], pw[1], pw[2], pw[3]);
  *(uint4*)&dst[16] = make_uint4(pw[4], pw[5], pw[6], pw[7]);
#pragma unroll
  for (int m = 16; m >= 1; m >>= 1) psum += __shfl_xor(psum, m);
  if (jseg == 0) D[((size_t)(b * 8 + oh) << 10) + i] = psum;
}

// ---------- Kernel 4: Z = (P @ V) / D per (b,h), fp8 MFMA ----------
// Tile M=128, N=64 (full hd), K-loop 1024 in steps of 64. 4 waves 2x2 (N split 32).
__global__ __launch_bounds__(256) void k_av(const unsigned char* __restrict__ P8,
                                            const u16* __restrict__ V,
                                            const float* __restrict__ D,
                                            u16* __restrict__ Z) {
  const int bh = blockIdx.y, m0 = blockIdx.x * 128;
  const int b = bh >> 3, h = bh & 7;
  __shared__ __align__(16) unsigned char sA8[128 * 64];
  __shared__ __align__(16) unsigned char sVt[64 * 64];
  const int tid = threadIdx.x, lane = tid & 63, wid = tid >> 6;
  const int wr = wid >> 1, wc = wid & 1, l15 = lane & 15, l4 = lane >> 4;
  f32x4 acc[4][2] = {};
  for (int k0 = 0; k0 < 1024; k0 += 64) {
    __syncthreads();
    {  // stage A (P fp8), swizzled
      int row = tid >> 1, c0 = (tid & 1) * 32;
      const unsigned char* src =
          &P8[((size_t)bh << 20) + (size_t)(m0 + row) * 1024 + k0 + c0];
      uint4 a0 = *(const uint4*)src, a1 = *(const uint4*)(src + 16);
      u64 ul[4];
      ul[0] = (u64)a0.x | ((u64)a0.y << 32);
      ul[1] = (u64)a0.z | ((u64)a0.w << 32);
      ul[2] = (u64)a1.x | ((u64)a1.y << 32);
      ul[3] = (u64)a1.z | ((u64)a1.w << 32);
      int xr = row & 7, gb = c0 >> 3;
#pragma unroll
      for (int t = 0; t < 4; ++t)
        *(u64*)&sA8[row * 64 + ((gb + t) ^ xr) * 8] = ul[t];
    }
    {  // stage V^T as fp8, swizzled
      int j = tid >> 2, d0 = (tid & 3) * 16;
      const u16* src = &V[((size_t)bh << 16) + (size_t)(k0 + j) * 64 + d0];
      uint4 v0 = *(const uint4*)src, v1 = *(const uint4*)(src + 16);
      u32 wv[8] = {v0.x, v0.y, v0.z, v0.w, v1.x, v1.y, v1.z, v1.w};
#pragma unroll
      for (int t = 0; t < 8; ++t) {
        u32 p = (u32)__builtin_amdgcn_cvt_pk_fp8_f32(bflo(wv[t]), bfhi(wv[t]), 0, false);
        int da = d0 + t * 2, db = da + 1;
        sVt[da * 64 + (((j >> 3) ^ (da & 7)) << 3) + (j & 7)] = (unsigned char)(p & 0xff);
        sVt[db * 64 + (((j >> 3) ^ (db & 7)) << 3) + (j & 7)] = (unsigned char)((p >> 8) & 0xff);
      }
    }
    __syncthreads();
    long bfr[2][2];
#pragma unroll
    for (int nr = 0; nr < 2; ++nr) {
      int row = wc * 32 + nr * 16 + l15;
#pragma unroll
      for (int ks = 0; ks < 2; ++ks)
        bfr[nr][ks] = *(long*)&sVt[row * 64 + (((ks * 4 + l4) ^ (row & 7)) << 3)];
    }
#pragma unroll
    for (int mr = 0; mr < 4; ++mr) {
      int row = wr * 64 + mr * 16 + l15;
      long afr[2];
#pragma unroll
      for (int ks = 0; ks < 2; ++ks)
        afr[ks] = *(long*)&sA8[row * 64 + (((ks * 4 + l4) ^ (row & 7)) << 3)];
#pragma unroll
      for (int nr = 0; nr < 2; ++nr)
#pragma unroll
        for (int ks = 0; ks < 2; ++ks)
          acc[mr][nr] = __builtin_amdgcn_mfma_f32_16x16x32_fp8_fp8(afr[ks], bfr[nr][ks],
                                                                   acc[mr][nr], 0, 0, 0);
    }
  }
#pragma unroll
  for (int mr = 0; mr < 4; ++mr) {
    int mbase = m0 + wr * 64 + mr * 16 + l4 * 4;
    float dv[4];
#pragma unroll
    for (int r = 0; r < 4; ++r) dv[r] = 1.f / D[((size_t)bh << 10) + mbase + r];
#pragma unroll
    for (int nr = 0; nr < 2; ++nr) {
      int d = wc * 32 + nr * 16 + l15;
#pragma unroll
      for (int r = 0; r < 4; ++r)
        Z[((size_t)(b * 1024 + mbase + r)) * 512 + h * 64 + d] =
            f2bf(acc[mr][nr][r] * dv[r]);
    }
  }
}

// ---------- Kernel 5: out = Z @ W^T + b + x. M=8192, N=512, K=512 ----------
__global__ __launch_bounds__(256) void k_proj(const u16* __restrict__ Z,
                                              const float* __restrict__ w,
                                              const float* __restrict__ bias,
                                              const float* __restrict__ xin,
                                              float* __restrict__ out) {
  __shared__ u16 sAt[32][72];
  __shared__ float sBt[32][68];
  const int tid = threadIdx.x;
  const int m0 = blockIdx.x * 64, n0 = blockIdx.y * 64;
  const int ty = tid >> 4, tx = tid & 15;
  float acc[4][4] = {};
  for (int k0 = 0; k0 < 512; k0 += 32) {
    __syncthreads();
    for (int u = tid; u < 256; u += 256) {
      int row = u >> 2, q = u & 3;
      uint4 za = *(const uint4*)&Z[(size_t)(m0 + row) * 512 + k0 + q * 8];
      sAt[q * 8 + 0][row] = (u16)za.x; sAt[q * 8 + 1][row] = (u16)(za.x >> 16);
      sAt[q * 8 + 2][row] = (u16)za.y; sAt[q * 8 + 3][row] = (u16)(za.y >> 16);
      sAt[q * 8 + 4][row] = (u16)za.z; sAt[q * 8 + 5][row] = (u16)(za.z >> 16);
      sAt[q * 8 + 6][row] = (u16)za.w; sAt[q * 8 + 7][row] = (u16)(za.w >> 16);
    }
    for (int u = tid; u < 512; u += 256) {
      int row = u >> 3, q = u & 7;
      float4 vb = *(const float4*)&w[(size_t)(n0 + row) * 512 + k0 + q * 4];
      sBt[q * 4 + 0][row] = vb.x; sBt[q * 4 + 1][row] = vb.y;
      sBt[q * 4 + 2][row] = vb.z; sBt[q * 4 + 3][row] = vb.w;
    }
    __syncthreads();
#pragma unroll
    for (int k = 0; k < 32; ++k) {
      uint2 ua = *(const uint2*)&sAt[k][ty * 4];
      float4 b4 = *(const float4*)&sBt[k][tx * 4];
      float a[4] = {bflo(ua.x), bfhi(ua.x), bflo(ua.y), bfhi(ua.y)};
      float b[4] = {b4.x, b4.y, b4.z, b4.w};
#pragma unroll
      for (int i = 0; i < 4; ++i)
#pragma unroll
        for (int j = 0; j < 4; ++j) acc[i][j] += a[i] * b[j];
    }
  }
#pragma unroll
  for (int i = 0; i < 4; ++i) {
    int m = m0 + ty * 4 + i;
    int nn = n0 + tx * 4;
    size_t o = (size_t)m * 512 + nn;
    float4 rres = *(const float4*)&xin[o];
    *(float4*)&out[o] = make_float4(acc[i][0] + bias[nn + 0] + rres.x,
                                    acc[i][1] + bias[nn + 1] + rres.y,
                                    acc[i][2] + bias[nn + 2] + rres.z,
                                    acc[i][3] + bias[nn + 3] + rres.w);
  }
}

extern "C" void kernel_launch(void* const* d_in, const int* in_sizes, int n_in,
                              void* d_out, int out_size, void* d_ws, size_t ws_size,
                              hipStream_t stream) {
  const size_t need = 160ull << 20;
  if (ws_size < need) return;  // clean diagnostic failure instead of GPU fault

  const float* x      = (const float*)d_in[0];
  const float* qkv_w  = (const float*)d_in[1];
  const float* proj_w = (const float*)d_in[2];
  const float* proj_b = (const float*)d_in[3];
  const float* conv_w = (const float*)d_in[4];
  const float* conv_b = (const float*)d_in[5];
  const float* bn_g   = (const float*)d_in[6];
  const float* bn_b   = (const float*)d_in[7];
  const float* bn_m   = (const float*)d_in[8];
  const float* bn_v   = (const float*)d_in[9];
  float* out = (float*)d_out;

  char* W = (char*)d_ws;
  u16* Wq = (u16*)W;                       // Q bf16, 8MB; dead after k_qk
  float* Dbuf = (float*)W;                 // D f32 256KB, overlays Q region
  u16* Wk = (u16*)(W + (8ull << 20));
  u16* Wv = (u16*)(W + (16ull << 20));
  u16* Wz = (u16*)(W + (24ull << 20));
  unsigned char* S8 = (unsigned char*)(W + (32ull << 20));  // 64MB
  unsigned char* P8 = (unsigned char*)(W + (96ull << 20));  // 64MB

  k_qkv<<<dim3(128, 24), 256, 0, stream>>>(x, qkv_w, Wq, Wk, Wv);
  k_qk<<<dim3(8, 8, 64), 256, 0, stream>>>(Wq, Wk, S8);
  k_conv<<<dim3(8192), 256, 0, stream>>>(S8, P8, Dbuf, conv_w, conv_b, bn_g, bn_b,
                                         bn_m, bn_v);
  k_av<<<dim3(8, 64), 256, 0, stream>>>(P8, Wv, Dbuf, Wz);
  k_proj<<<dim3(128, 8), 256, 0, stream>>>(Wz, proj_w, proj_b, x, out);
}

// Round 7
// 351.460 us; speedup vs baseline: 5.5268x; 1.8110x over previous
//
#include <hip/hip_runtime.h>

// GuidedAttention on MI355X, round 7: resubmission of round 6 (infra failure,
// code never ran). b=8, n=1024, c=512, H=8, hd=64.
// ws layout (160 MB): [Q bf16 8MB | D f32 256KB overlaid after k_qk]
//                     [K bf16 8MB][V bf16 8MB][Z bf16 8MB]
//                     [S fp8 64MB][P fp8 64MB]
// Pipeline: k_qkv (bf16 MFMA) -> k_qk (bf16 MFMA -> S fp8)
//        -> k_conv (conv+bn+sigmoid+exp -> P fp8, D f32; conflict-free)
//        -> k_av (fp8 MFMA, /D -> Z bf16) -> k_proj (bf16 MFMA + residual).

#define DINL __device__ __forceinline__
typedef unsigned short u16;
typedef unsigned int u32;
typedef unsigned long long u64;
typedef short bf16x8 __attribute__((ext_vector_type(8)));
typedef float f32x4 __attribute__((ext_vector_type(4)));
typedef float f32x2 __attribute__((ext_vector_type(2)));

DINL u16 f2bf(float f) {
  u32 u = __float_as_uint(f);
  u += 0x7fffu + ((u >> 16) & 1u);
  return (u16)(u >> 16);
}
DINL float bflo(u32 u) { return __uint_as_float(u << 16); }
DINL float bfhi(u32 u) { return __uint_as_float(u & 0xffff0000u); }
DINL u32 cvtpk_bf16(float lo, float hi) {
  u32 r;
  asm("v_cvt_pk_bf16_f32 %0, %1, %2" : "=v"(r) : "v"(lo), "v"(hi));
  return r;
}
DINL u32 pk4_fp8(float a, float b, float c, float d) {
  u32 r = 0;
  r = (u32)__builtin_amdgcn_cvt_pk_fp8_f32(a, b, (int)r, false);
  r = (u32)__builtin_amdgcn_cvt_pk_fp8_f32(c, d, (int)r, true);
  return r;
}
DINL f32x2 up2_lo(u32 w) { return __builtin_amdgcn_cvt_pk_f32_fp8((int)w, false); }
DINL f32x2 up2_hi(u32 w) { return __builtin_amdgcn_cvt_pk_f32_fp8((int)w, true); }
DINL unsigned char f2fp8(float v) {
  return (unsigned char)((u32)__builtin_amdgcn_cvt_pk_fp8_f32(v, v, 0, false) & 0xffu);
}

// ---------- Kernel 1: QKV proj, bf16 MFMA. M=8192, N=1536, K=512 ----------
// 128x128 tile, BK=64, 4 waves 2x2. fp32 inputs converted at stage.
__global__ __launch_bounds__(256) void k_qkv(const float* __restrict__ x,
                                             const float* __restrict__ w,
                                             u16* __restrict__ Q,
                                             u16* __restrict__ K,
                                             u16* __restrict__ V) {
  __shared__ __align__(16) u16 sA[128 * 64];
  __shared__ __align__(16) u16 sB[128 * 64];
  const int tid = threadIdx.x;
  const int m0 = blockIdx.x * 128, n0 = blockIdx.y * 128;
  const int lane = tid & 63, wid = tid >> 6;
  const int wr = wid >> 1, wc = wid & 1;
  const int l15 = lane & 15, l4 = lane >> 4;
  const int row = tid >> 1, half = tid & 1, xr = row & 7;
  f32x4 acc[4][4] = {};
  for (int k0 = 0; k0 < 512; k0 += 64) {
    __syncthreads();
    {
      const float* ga = &x[(size_t)(m0 + row) * 512 + k0 + half * 32];
      const float* gb = &w[(size_t)(n0 + row) * 512 + k0 + half * 32];
#pragma unroll
      for (int q = 0; q < 4; ++q) {
        int gp = (half * 4 + q) ^ xr;
        float4 a0 = *(const float4*)&ga[q * 8];
        float4 a1 = *(const float4*)&ga[q * 8 + 4];
        uint4 pa;
        pa.x = cvtpk_bf16(a0.x, a0.y); pa.y = cvtpk_bf16(a0.z, a0.w);
        pa.z = cvtpk_bf16(a1.x, a1.y); pa.w = cvtpk_bf16(a1.z, a1.w);
        *(uint4*)&sA[row * 64 + gp * 8] = pa;
        float4 b0 = *(const float4*)&gb[q * 8];
        float4 b1 = *(const float4*)&gb[q * 8 + 4];
        uint4 pb;
        pb.x = cvtpk_bf16(b0.x, b0.y); pb.y = cvtpk_bf16(b0.z, b0.w);
        pb.z = cvtpk_bf16(b1.x, b1.y); pb.w = cvtpk_bf16(b1.z, b1.w);
        *(uint4*)&sB[row * 64 + gp * 8] = pb;
      }
    }
    __syncthreads();
#pragma unroll
    for (int ks = 0; ks < 2; ++ks) {
      bf16x8 af[4], bfr[4];
#pragma unroll
      for (int mr = 0; mr < 4; ++mr) {
        int rr = wr * 64 + mr * 16 + l15;
        af[mr] = *(bf16x8*)&sA[rr * 64 + ((ks * 4 + l4) ^ (rr & 7)) * 8];
      }
#pragma unroll
      for (int nr = 0; nr < 4; ++nr) {
        int rr = wc * 64 + nr * 16 + l15;
        bfr[nr] = *(bf16x8*)&sB[rr * 64 + ((ks * 4 + l4) ^ (rr & 7)) * 8];
      }
#pragma unroll
      for (int mr = 0; mr < 4; ++mr)
#pragma unroll
        for (int nr = 0; nr < 4; ++nr)
          acc[mr][nr] = __builtin_amdgcn_mfma_f32_16x16x32_bf16(af[mr], bfr[nr],
                                                                acc[mr][nr], 0, 0, 0);
    }
  }
#pragma unroll
  for (int nr = 0; nr < 4; ++nr) {
    int nn = n0 + wc * 64 + nr * 16 + l15;
    int which = nn >> 9, co = nn & 511;
    int head = co >> 6, d = co & 63;
    u16* dst = (which == 0) ? Q : (which == 1) ? K : V;
    float sc = (which == 0) ? 0.125f : 1.f;
#pragma unroll
    for (int mr = 0; mr < 4; ++mr) {
      int mb = m0 + wr * 64 + mr * 16 + l4 * 4;
#pragma unroll
      for (int r = 0; r < 4; ++r) {
        int m = mb + r;
        int bb = m >> 10, ii = m & 1023;
        dst[((((size_t)bb * 8 + head) << 10) + ii) * 64 + d] =
            f2bf(acc[mr][nr][r] * sc);
      }
    }
  }
}

// ---------- Kernel 2: S = Q @ K^T per (b,h), bf16 MFMA, out fp8 ----------
__global__ __launch_bounds__(256) void k_qk(const u16* __restrict__ Q,
                                            const u16* __restrict__ Kp,
                                            unsigned char* __restrict__ S8) {
  const int bh = blockIdx.z;
  const u16* Qb = Q + (size_t)bh * 65536;
  const u16* Kb = Kp + (size_t)bh * 65536;
  __shared__ __align__(16) u16 sQ[128 * 64];
  __shared__ __align__(16) u16 sK[128 * 64];
  const int tid = threadIdx.x;
  const int m0 = blockIdx.x * 128, n0 = blockIdx.y * 128;
  {
    int row = tid >> 1, half = tid & 1;
    const u16* gq = &Qb[(size_t)(m0 + row) * 64 + half * 32];
    const u16* gk = &Kb[(size_t)(n0 + row) * 64 + half * 32];
    int xr = row & 7;
#pragma unroll
    for (int q = 0; q < 4; ++q) {
      int gp = (half * 4 + q) ^ xr;
      *(uint4*)&sQ[row * 64 + gp * 8] = *(const uint4*)&gq[q * 8];
      *(uint4*)&sK[row * 64 + gp * 8] = *(const uint4*)&gk[q * 8];
    }
  }
  __syncthreads();
  const int lane = tid & 63, wid = tid >> 6;
  const int wr = wid >> 1, wc = wid & 1;
  const int l15 = lane & 15, l4 = lane >> 4;
  f32x4 acc[4][4] = {};
  bf16x8 af[4][2], bf[4][2];
#pragma unroll
  for (int mr = 0; mr < 4; ++mr) {
    int row = wr * 64 + mr * 16 + l15;
#pragma unroll
    for (int ks = 0; ks < 2; ++ks)
      af[mr][ks] = *(bf16x8*)&sQ[row * 64 + ((ks * 4 + l4) ^ (row & 7)) * 8];
  }
#pragma unroll
  for (int nr = 0; nr < 4; ++nr) {
    int row = wc * 64 + nr * 16 + l15;
#pragma unroll
    for (int ks = 0; ks < 2; ++ks)
      bf[nr][ks] = *(bf16x8*)&sK[row * 64 + ((ks * 4 + l4) ^ (row & 7)) * 8];
  }
#pragma unroll
  for (int mr = 0; mr < 4; ++mr)
#pragma unroll
    for (int nr = 0; nr < 4; ++nr)
#pragma unroll
      for (int ks = 0; ks < 2; ++ks)
        acc[mr][nr] = __builtin_amdgcn_mfma_f32_16x16x32_bf16(af[mr][ks], bf[nr][ks],
                                                              acc[mr][nr], 0, 0, 0);
  __syncthreads();
  unsigned char* t8 = (unsigned char*)sQ;  // reuse 16KB as fp8 [128][128]
#pragma unroll
  for (int mr = 0; mr < 4; ++mr) {
    int mloc = wr * 64 + mr * 16 + l4 * 4;
#pragma unroll
    for (int nr = 0; nr < 4; ++nr) {
      int nloc = wc * 64 + nr * 16 + l15;
#pragma unroll
      for (int r = 0; r < 4; ++r)
        t8[(mloc + r) * 128 + nloc] = f2fp8(acc[mr][nr][r]);
    }
  }
  __syncthreads();
  {
    int row = tid >> 1, c0 = (tid & 1) * 64;
    unsigned char* dst = &S8[((size_t)bh << 20) + (size_t)(m0 + row) * 1024 + n0 + c0];
#pragma unroll
    for (int q = 0; q < 4; ++q)
      *(uint4*)&dst[q * 16] = *(uint4*)&t8[row * 128 + c0 + q * 16];
  }
}

// ---------- Kernel 3: conv3x3(heads)+BN+sigmoid+exp -> P fp8, D f32 ----------
// Block per (b,i). S kept fp8 in LDS (24KB). Thread t -> 4 cols, all 8 oh.
// u32 reads at lane stride 4B -> 2-way bank access (free).
__global__ __launch_bounds__(256) void k_conv(
    const unsigned char* __restrict__ S8, unsigned char* __restrict__ P8,
    float* __restrict__ D, const float* __restrict__ cw,
    const float* __restrict__ cb, const float* __restrict__ bg,
    const float* __restrict__ bb, const float* __restrict__ bm,
    const float* __restrict__ bv) {
  const int b = blockIdx.x >> 10, i = blockIdx.x & 1023;
  __shared__ __align__(16) unsigned char sS[24 * 1024];  // [g=ih*3+dr][1024]
  __shared__ float sW2[24][8][3];                        // [g][oh][tap]
  __shared__ float sRed[4][8];
  const int tid = threadIdx.x;
  for (int u = tid; u < 576; u += 256) {
    int tap = u % 3, rest = u / 3;
    int dr = rest % 3, r2 = rest / 3;
    int ih = r2 & 7, oh = r2 >> 3;
    sW2[ih * 3 + dr][oh][tap] = cw[u];
  }
  for (int u = tid; u < 1536; u += 256) {  // 1536 uint4 = 24KB
    int g = u >> 6, q = u & 63;
    int ih = g / 3, dr = g - ih * 3;
    int srow = i - 1 + dr;
    uint4 v = make_uint4(0, 0, 0, 0);
    if (srow >= 0 && srow < 1024)
      v = *(const uint4*)&S8[((size_t)(b * 8 + ih) << 20) + (size_t)srow * 1024 + q * 16];
    *(uint4*)&sS[g * 1024 + q * 16] = v;
  }
  __syncthreads();
  const int j0 = tid * 4;
  float acc[8][4];
#pragma unroll
  for (int oh = 0; oh < 8; ++oh)
#pragma unroll
    for (int kk = 0; kk < 4; ++kk) acc[oh][kk] = 0.f;
#pragma unroll 4
  for (int g = 0; g < 24; ++g) {
    const unsigned char* rb = &sS[g * 1024];
    u32 wd = *(const u32*)&rb[j0];
    f32x2 lo = up2_lo(wd), hi = up2_hi(wd);
    float sv[6];
    sv[0] = (tid > 0) ? up2_lo((u32)rb[j0 - 1]).x : 0.f;
    sv[1] = lo.x; sv[2] = lo.y; sv[3] = hi.x; sv[4] = hi.y;
    sv[5] = (tid < 255) ? up2_lo((u32)rb[j0 + 4]).x : 0.f;
#pragma unroll
    for (int oh = 0; oh < 8; ++oh) {
      float w0 = sW2[g][oh][0], w1 = sW2[g][oh][1], w2 = sW2[g][oh][2];
#pragma unroll
      for (int kk = 0; kk < 4; ++kk)
        acc[oh][kk] += w0 * sv[kk] + w1 * sv[kk + 1] + w2 * sv[kk + 2];
    }
  }
  float psum[8];
#pragma unroll
  for (int oh = 0; oh < 8; ++oh) {
    float ah = bg[oh] * rsqrtf(bv[oh] + 1e-5f);
    float bh2 = bb[oh] - bm[oh] * ah;
    float bias = cb[oh];
    float e[4];
#pragma unroll
    for (int kk = 0; kk < 4; ++kk) {
      float t = (acc[oh][kk] + bias) * ah + bh2;
      float p = 1.f / (1.f + __expf(-t));
      e[kk] = __expf(p);  // softmax numerator; p in (0,1) so no max needed
    }
    u32 pw = pk4_fp8(e[0], e[1], e[2], e[3]);
    *(u32*)&P8[((size_t)(b * 8 + oh) << 20) + (size_t)i * 1024 + j0] = pw;
    // denominator from QUANTIZED numerators for exact normalization
    f32x2 dlo = up2_lo(pw), dhi = up2_hi(pw);
    psum[oh] = (dlo.x + dlo.y) + (dhi.x + dhi.y);
  }
  const int lane = tid & 63, wv = tid >> 6;
#pragma unroll
  for (int oh = 0; oh < 8; ++oh) {
    float p = psum[oh];
#pragma unroll
    for (int m = 32; m >= 1; m >>= 1) p += __shfl_xor(p, m);
    if (lane == 0) sRed[wv][oh] = p;
  }
  __syncthreads();
  if (tid < 8)
    D[((size_t)(b * 8 + tid) << 10) + i] =
        sRed[0][tid] + sRed[1][tid] + sRed[2][tid] + sRed[3][tid];
}

// ---------- Kernel 4: Z = (P @ V) / D per (b,h), fp8 MFMA ----------
__global__ __launch_bounds__(256) void k_av(const unsigned char* __restrict__ P8,
                                            const u16* __restrict__ V,
                                            const float* __restrict__ D,
                                            u16* __restrict__ Z) {
  const int bh = blockIdx.y, m0 = blockIdx.x * 128;
  const int b = bh >> 3, h = bh & 7;
  __shared__ __align__(16) unsigned char sA8[128 * 64];
  __shared__ __align__(16) unsigned char sVt[64 * 64];
  const int tid = threadIdx.x, lane = tid & 63, wid = tid >> 6;
  const int wr = wid >> 1, wc = wid & 1, l15 = lane & 15, l4 = lane >> 4;
  f32x4 acc[4][2] = {};
  for (int k0 = 0; k0 < 1024; k0 += 64) {
    __syncthreads();
    {  // stage A (P fp8), swizzled
      int row = tid >> 1, c0 = (tid & 1) * 32;
      const unsigned char* src =
          &P8[((size_t)bh << 20) + (size_t)(m0 + row) * 1024 + k0 + c0];
      uint4 a0 = *(const uint4*)src, a1 = *(const uint4*)(src + 16);
      u64 ul[4];
      ul[0] = (u64)a0.x | ((u64)a0.y << 32);
      ul[1] = (u64)a0.z | ((u64)a0.w << 32);
      ul[2] = (u64)a1.x | ((u64)a1.y << 32);
      ul[3] = (u64)a1.z | ((u64)a1.w << 32);
      int xr = row & 7, gb = c0 >> 3;
#pragma unroll
      for (int t = 0; t < 4; ++t)
        *(u64*)&sA8[row * 64 + ((gb + t) ^ xr) * 8] = ul[t];
    }
    {  // stage V^T as fp8, swizzled
      int j = tid >> 2, d0 = (tid & 3) * 16;
      const u16* src = &V[((size_t)bh << 16) + (size_t)(k0 + j) * 64 + d0];
      uint4 v0 = *(const uint4*)src, v1 = *(const uint4*)(src + 16);
      u32 wv[8] = {v0.x, v0.y, v0.z, v0.w, v1.x, v1.y, v1.z, v1.w};
#pragma unroll
      for (int t = 0; t < 8; ++t) {
        u32 p = (u32)__builtin_amdgcn_cvt_pk_fp8_f32(bflo(wv[t]), bfhi(wv[t]), 0, false);
        int da = d0 + t * 2, db = da + 1;
        sVt[da * 64 + (((j >> 3) ^ (da & 7)) << 3) + (j & 7)] = (unsigned char)(p & 0xff);
        sVt[db * 64 + (((j >> 3) ^ (db & 7)) << 3) + (j & 7)] = (unsigned char)((p >> 8) & 0xff);
      }
    }
    __syncthreads();
    long bfr[2][2];
#pragma unroll
    for (int nr = 0; nr < 2; ++nr) {
      int row = wc * 32 + nr * 16 + l15;
#pragma unroll
      for (int ks = 0; ks < 2; ++ks)
        bfr[nr][ks] = *(long*)&sVt[row * 64 + (((ks * 4 + l4) ^ (row & 7)) << 3)];
    }
#pragma unroll
    for (int mr = 0; mr < 4; ++mr) {
      int row = wr * 64 + mr * 16 + l15;
      long afr[2];
#pragma unroll
      for (int ks = 0; ks < 2; ++ks)
        afr[ks] = *(long*)&sA8[row * 64 + (((ks * 4 + l4) ^ (row & 7)) << 3)];
#pragma unroll
      for (int nr = 0; nr < 2; ++nr)
#pragma unroll
        for (int ks = 0; ks < 2; ++ks)
          acc[mr][nr] = __builtin_amdgcn_mfma_f32_16x16x32_fp8_fp8(afr[ks], bfr[nr][ks],
                                                                   acc[mr][nr], 0, 0, 0);
    }
  }
#pragma unroll
  for (int mr = 0; mr < 4; ++mr) {
    int mbase = m0 + wr * 64 + mr * 16 + l4 * 4;
    float dv[4];
#pragma unroll
    for (int r = 0; r < 4; ++r) dv[r] = 1.f / D[((size_t)bh << 10) + mbase + r];
#pragma unroll
    for (int nr = 0; nr < 2; ++nr) {
      int d = wc * 32 + nr * 16 + l15;
#pragma unroll
      for (int r = 0; r < 4; ++r)
        Z[((size_t)(b * 1024 + mbase + r)) * 512 + h * 64 + d] =
            f2bf(acc[mr][nr][r] * dv[r]);
    }
  }
}

// ---------- Kernel 5: out = Z @ W^T + b + x, bf16 MFMA. M=8192,N=512,K=512 ----------
__global__ __launch_bounds__(256) void k_proj(const u16* __restrict__ Z,
                                              const float* __restrict__ w,
                                              const float* __restrict__ bias,
                                              const float* __restrict__ xin,
                                              float* __restrict__ out) {
  __shared__ __align__(16) u16 sA[128 * 64];
  __shared__ __align__(16) u16 sB[128 * 64];
  const int tid = threadIdx.x;
  const int m0 = blockIdx.x * 128, n0 = blockIdx.y * 128;
  const int lane = tid & 63, wid = tid >> 6;
  const int wr = wid >> 1, wc = wid & 1;
  const int l15 = lane & 15, l4 = lane >> 4;
  const int row = tid >> 1, half = tid & 1, xr = row & 7;
  f32x4 acc[4][4] = {};
  for (int k0 = 0; k0 < 512; k0 += 64) {
    __syncthreads();
    {
      const u16* gz = &Z[(size_t)(m0 + row) * 512 + k0 + half * 32];
      const float* gb = &w[(size_t)(n0 + row) * 512 + k0 + half * 32];
#pragma unroll
      for (int q = 0; q < 4; ++q) {
        int gp = (half * 4 + q) ^ xr;
        *(uint4*)&sA[row * 64 + gp * 8] = *(const uint4*)&gz[q * 8];
        float4 b0 = *(const float4*)&gb[q * 8];
        float4 b1 = *(const float4*)&gb[q * 8 + 4];
        uint4 pb;
        pb.x = cvtpk_bf16(b0.x, b0.y); pb.y = cvtpk_bf16(b0.z, b0.w);
        pb.z = cvtpk_bf16(b1.x, b1.y); pb.w = cvtpk_bf16(b1.z, b1.w);
        *(uint4*)&sB[row * 64 + gp * 8] = pb;
      }
    }
    __syncthreads();
#pragma unroll
    for (int ks = 0; ks < 2; ++ks) {
      bf16x8 af[4], bfr[4];
#pragma unroll
      for (int mr = 0; mr < 4; ++mr) {
        int rr = wr * 64 + mr * 16 + l15;
        af[mr] = *(bf16x8*)&sA[rr * 64 + ((ks * 4 + l4) ^ (rr & 7)) * 8];
      }
#pragma unroll
      for (int nr = 0; nr < 4; ++nr) {
        int rr = wc * 64 + nr * 16 + l15;
        bfr[nr] = *(bf16x8*)&sB[rr * 64 + ((ks * 4 + l4) ^ (rr & 7)) * 8];
      }
#pragma unroll
      for (int mr = 0; mr < 4; ++mr)
#pragma unroll
        for (int nr = 0; nr < 4; ++nr)
          acc[mr][nr] = __builtin_amdgcn_mfma_f32_16x16x32_bf16(af[mr], bfr[nr],
                                                                acc[mr][nr], 0, 0, 0);
    }
  }
#pragma unroll
  for (int nr = 0; nr < 4; ++nr) {
    int nn = n0 + wc * 64 + nr * 16 + l15;
    float bv2 = bias[nn];
#pragma unroll
    for (int mr = 0; mr < 4; ++mr) {
      int mb = m0 + wr * 64 + mr * 16 + l4 * 4;
#pragma unroll
      for (int r = 0; r < 4; ++r) {
        size_t o = (size_t)(mb + r) * 512 + nn;
        out[o] = acc[mr][nr][r] + bv2 + xin[o];
      }
    }
  }
}

extern "C" void kernel_launch(void* const* d_in, const int* in_sizes, int n_in,
                              void* d_out, int out_size, void* d_ws, size_t ws_size,
                              hipStream_t stream) {
  const size_t need = 160ull << 20;
  if (ws_size < need) return;  // clean diagnostic failure instead of GPU fault

  const float* x      = (const float*)d_in[0];
  const float* qkv_w  = (const float*)d_in[1];
  const float* proj_w = (const float*)d_in[2];
  const float* proj_b = (const float*)d_in[3];
  const float* conv_w = (const float*)d_in[4];
  const float* conv_b = (const float*)d_in[5];
  const float* bn_g   = (const float*)d_in[6];
  const float* bn_b   = (const float*)d_in[7];
  const float* bn_m   = (const float*)d_in[8];
  const float* bn_v   = (const float*)d_in[9];
  float* out = (float*)d_out;

  char* W = (char*)d_ws;
  u16* Wq = (u16*)W;                       // Q bf16 8MB; dead after k_qk
  float* Dbuf = (float*)W;                 // D f32 256KB, overlays Q region
  u16* Wk = (u16*)(W + (8ull << 20));
  u16* Wv = (u16*)(W + (16ull << 20));
  u16* Wz = (u16*)(W + (24ull << 20));
  unsigned char* S8 = (unsigned char*)(W + (32ull << 20));  // 64MB
  unsigned char* P8 = (unsigned char*)(W + (96ull << 20));  // 64MB

  k_qkv<<<dim3(64, 12), 256, 0, stream>>>(x, qkv_w, Wq, Wk, Wv);
  k_qk<<<dim3(8, 8, 64), 256, 0, stream>>>(Wq, Wk, S8);
  k_conv<<<dim3(8192), 256, 0, stream>>>(S8, P8, Dbuf, conv_w, conv_b, bn_g, bn_b,
                                         bn_m, bn_v);
  k_av<<<dim3(8, 64), 256, 0, stream>>>(P8, Wv, Dbuf, Wz);
  k_proj<<<dim3(64, 4), 256, 0, stream>>>(Wz, proj_w, proj_b, x, out);
}

// Round 8
// 261.684 us; speedup vs baseline: 7.4228x; 1.3431x over previous
//
#include <hip/hip_runtime.h>

// GuidedAttention on MI355X, round 8: k_conv rebuilt as an MFMA GEMM
// (M=16 = 2 rows x 8 out-heads, K=96 = 3 taps x 8 in-heads x 4 staged rows,
// N=1024 cols; col-major LDS staging so tap shifts are address offsets).
// All other kernels unchanged from the validated round-7 build.
// b=8, n=1024, c=512, H=8, hd=64.
// ws layout (160 MB): [Q bf16 8MB | D f32 256KB overlaid after k_qk]
//                     [K bf16 8MB][V bf16 8MB][Z bf16 8MB]
//                     [S fp8 64MB][P fp8 64MB]

#define DINL __device__ __forceinline__
typedef unsigned short u16;
typedef unsigned int u32;
typedef unsigned long long u64;
typedef short bf16x8 __attribute__((ext_vector_type(8)));
typedef float f32x4 __attribute__((ext_vector_type(4)));
typedef float f32x2 __attribute__((ext_vector_type(2)));

DINL u16 f2bf(float f) {
  u32 u = __float_as_uint(f);
  u += 0x7fffu + ((u >> 16) & 1u);
  return (u16)(u >> 16);
}
DINL float bflo(u32 u) { return __uint_as_float(u << 16); }
DINL float bfhi(u32 u) { return __uint_as_float(u & 0xffff0000u); }
DINL u32 cvtpk_bf16(float lo, float hi) {
  u32 r;
  asm("v_cvt_pk_bf16_f32 %0, %1, %2" : "=v"(r) : "v"(lo), "v"(hi));
  return r;
}
DINL u32 pk4_fp8(float a, float b, float c, float d) {
  u32 r = 0;
  r = (u32)__builtin_amdgcn_cvt_pk_fp8_f32(a, b, (int)r, false);
  r = (u32)__builtin_amdgcn_cvt_pk_fp8_f32(c, d, (int)r, true);
  return r;
}
DINL f32x2 up2_lo(u32 w) { return __builtin_amdgcn_cvt_pk_f32_fp8((int)w, false); }
DINL f32x2 up2_hi(u32 w) { return __builtin_amdgcn_cvt_pk_f32_fp8((int)w, true); }
DINL unsigned char f2fp8(float v) {
  return (unsigned char)((u32)__builtin_amdgcn_cvt_pk_fp8_f32(v, v, 0, false) & 0xffu);
}

// ---------- Kernel 1: QKV proj, bf16 MFMA. M=8192, N=1536, K=512 ----------
__global__ __launch_bounds__(256) void k_qkv(const float* __restrict__ x,
                                             const float* __restrict__ w,
                                             u16* __restrict__ Q,
                                             u16* __restrict__ K,
                                             u16* __restrict__ V) {
  __shared__ __align__(16) u16 sA[128 * 64];
  __shared__ __align__(16) u16 sB[128 * 64];
  const int tid = threadIdx.x;
  const int m0 = blockIdx.x * 128, n0 = blockIdx.y * 128;
  const int lane = tid & 63, wid = tid >> 6;
  const int wr = wid >> 1, wc = wid & 1;
  const int l15 = lane & 15, l4 = lane >> 4;
  const int row = tid >> 1, half = tid & 1, xr = row & 7;
  f32x4 acc[4][4] = {};
  for (int k0 = 0; k0 < 512; k0 += 64) {
    __syncthreads();
    {
      const float* ga = &x[(size_t)(m0 + row) * 512 + k0 + half * 32];
      const float* gb = &w[(size_t)(n0 + row) * 512 + k0 + half * 32];
#pragma unroll
      for (int q = 0; q < 4; ++q) {
        int gp = (half * 4 + q) ^ xr;
        float4 a0 = *(const float4*)&ga[q * 8];
        float4 a1 = *(const float4*)&ga[q * 8 + 4];
        uint4 pa;
        pa.x = cvtpk_bf16(a0.x, a0.y); pa.y = cvtpk_bf16(a0.z, a0.w);
        pa.z = cvtpk_bf16(a1.x, a1.y); pa.w = cvtpk_bf16(a1.z, a1.w);
        *(uint4*)&sA[row * 64 + gp * 8] = pa;
        float4 b0 = *(const float4*)&gb[q * 8];
        float4 b1 = *(const float4*)&gb[q * 8 + 4];
        uint4 pb;
        pb.x = cvtpk_bf16(b0.x, b0.y); pb.y = cvtpk_bf16(b0.z, b0.w);
        pb.z = cvtpk_bf16(b1.x, b1.y); pb.w = cvtpk_bf16(b1.z, b1.w);
        *(uint4*)&sB[row * 64 + gp * 8] = pb;
      }
    }
    __syncthreads();
#pragma unroll
    for (int ks = 0; ks < 2; ++ks) {
      bf16x8 af[4], bfr[4];
#pragma unroll
      for (int mr = 0; mr < 4; ++mr) {
        int rr = wr * 64 + mr * 16 + l15;
        af[mr] = *(bf16x8*)&sA[rr * 64 + ((ks * 4 + l4) ^ (rr & 7)) * 8];
      }
#pragma unroll
      for (int nr = 0; nr < 4; ++nr) {
        int rr = wc * 64 + nr * 16 + l15;
        bfr[nr] = *(bf16x8*)&sB[rr * 64 + ((ks * 4 + l4) ^ (rr & 7)) * 8];
      }
#pragma unroll
      for (int mr = 0; mr < 4; ++mr)
#pragma unroll
        for (int nr = 0; nr < 4; ++nr)
          acc[mr][nr] = __builtin_amdgcn_mfma_f32_16x16x32_bf16(af[mr], bfr[nr],
                                                                acc[mr][nr], 0, 0, 0);
    }
  }
#pragma unroll
  for (int nr = 0; nr < 4; ++nr) {
    int nn = n0 + wc * 64 + nr * 16 + l15;
    int which = nn >> 9, co = nn & 511;
    int head = co >> 6, d = co & 63;
    u16* dst = (which == 0) ? Q : (which == 1) ? K : V;
    float sc = (which == 0) ? 0.125f : 1.f;
#pragma unroll
    for (int mr = 0; mr < 4; ++mr) {
      int mb = m0 + wr * 64 + mr * 16 + l4 * 4;
#pragma unroll
      for (int r = 0; r < 4; ++r) {
        int m = mb + r;
        int bb = m >> 10, ii = m & 1023;
        dst[((((size_t)bb * 8 + head) << 10) + ii) * 64 + d] =
            f2bf(acc[mr][nr][r] * sc);
      }
    }
  }
}

// ---------- Kernel 2: S = Q @ K^T per (b,h), bf16 MFMA, out fp8 ----------
__global__ __launch_bounds__(256) void k_qk(const u16* __restrict__ Q,
                                            const u16* __restrict__ Kp,
                                            unsigned char* __restrict__ S8) {
  const int bh = blockIdx.z;
  const u16* Qb = Q + (size_t)bh * 65536;
  const u16* Kb = Kp + (size_t)bh * 65536;
  __shared__ __align__(16) u16 sQ[128 * 64];
  __shared__ __align__(16) u16 sK[128 * 64];
  const int tid = threadIdx.x;
  const int m0 = blockIdx.x * 128, n0 = blockIdx.y * 128;
  {
    int row = tid >> 1, half = tid & 1;
    const u16* gq = &Qb[(size_t)(m0 + row) * 64 + half * 32];
    const u16* gk = &Kb[(size_t)(n0 + row) * 64 + half * 32];
    int xr = row & 7;
#pragma unroll
    for (int q = 0; q < 4; ++q) {
      int gp = (half * 4 + q) ^ xr;
      *(uint4*)&sQ[row * 64 + gp * 8] = *(const uint4*)&gq[q * 8];
      *(uint4*)&sK[row * 64 + gp * 8] = *(const uint4*)&gk[q * 8];
    }
  }
  __syncthreads();
  const int lane = tid & 63, wid = tid >> 6;
  const int wr = wid >> 1, wc = wid & 1;
  const int l15 = lane & 15, l4 = lane >> 4;
  f32x4 acc[4][4] = {};
  bf16x8 af[4][2], bf[4][2];
#pragma unroll
  for (int mr = 0; mr < 4; ++mr) {
    int row = wr * 64 + mr * 16 + l15;
#pragma unroll
    for (int ks = 0; ks < 2; ++ks)
      af[mr][ks] = *(bf16x8*)&sQ[row * 64 + ((ks * 4 + l4) ^ (row & 7)) * 8];
  }
#pragma unroll
  for (int nr = 0; nr < 4; ++nr) {
    int row = wc * 64 + nr * 16 + l15;
#pragma unroll
    for (int ks = 0; ks < 2; ++ks)
      bf[nr][ks] = *(bf16x8*)&sK[row * 64 + ((ks * 4 + l4) ^ (row & 7)) * 8];
  }
#pragma unroll
  for (int mr = 0; mr < 4; ++mr)
#pragma unroll
    for (int nr = 0; nr < 4; ++nr)
#pragma unroll
      for (int ks = 0; ks < 2; ++ks)
        acc[mr][nr] = __builtin_amdgcn_mfma_f32_16x16x32_bf16(af[mr][ks], bf[nr][ks],
                                                              acc[mr][nr], 0, 0, 0);
  __syncthreads();
  unsigned char* t8 = (unsigned char*)sQ;  // reuse 16KB as fp8 [128][128]
#pragma unroll
  for (int mr = 0; mr < 4; ++mr) {
    int mloc = wr * 64 + mr * 16 + l4 * 4;
#pragma unroll
    for (int nr = 0; nr < 4; ++nr) {
      int nloc = wc * 64 + nr * 16 + l15;
#pragma unroll
      for (int r = 0; r < 4; ++r)
        t8[(mloc + r) * 128 + nloc] = f2fp8(acc[mr][nr][r]);
    }
  }
  __syncthreads();
  {
    int row = tid >> 1, c0 = (tid & 1) * 64;
    unsigned char* dst = &S8[((size_t)bh << 20) + (size_t)(m0 + row) * 1024 + n0 + c0];
#pragma unroll
    for (int q = 0; q < 4; ++q)
      *(uint4*)&dst[q * 16] = *(uint4*)&t8[row * 128 + c0 + q * 16];
  }
}

// ---------- Kernel 3: conv3x3(heads)+BN+sigmoid+exp as MFMA GEMM ----------
// Block per (b, row-pair). M=16 rows = (p in {0,1}) x (oh in 0..7).
// K = 96: k = tap*32 + ih*4 + rr  (rr = staged row 0..3 = i0-1+rr).
// A[m][k] = ah[oh] * cw[oh][ih][rr-p][tap]  (0 if rr-p not in [0,3)).
// B[k][j] = S_fp8[b,ih,i0-1+rr, j+tap-1] staged col-major in LDS.
__global__ __launch_bounds__(256) void k_conv(
    const unsigned char* __restrict__ S8, unsigned char* __restrict__ P8,
    float* __restrict__ D, const float* __restrict__ cw,
    const float* __restrict__ cb, const float* __restrict__ bg,
    const float* __restrict__ bb, const float* __restrict__ bm,
    const float* __restrict__ bv) {
  const int b = blockIdx.x >> 9, ip = blockIdx.x & 511;
  const int i0 = ip * 2;
  __shared__ __align__(16) u16 sC[1027 * 34];  // [ci = col+1][g = ih*4+rr], 69.8KB
  __shared__ __align__(16) u16 sA[3][16][32];  // A-frags per tap
  __shared__ float sRedD[4][16];
  const int tid = threadIdx.x;
  const int lane = tid & 63, wid = tid >> 6;
  const int l15 = lane & 15, l4 = lane >> 4;

  // Build A (weights folded with BN scale), bf16.
  for (int u = tid; u < 1536; u += 256) {
    int tap = u >> 9, rem = u & 511;       // tap<3, rem = m*32 + kk
    int m = rem >> 5, kk = rem & 31;
    int p = m >> 3, oh = m & 7;
    int ih = kk >> 2, rr = kk & 3;
    int dr = rr - p;
    float v = 0.f;
    if (dr >= 0 && dr < 3) {
      float ah = bg[oh] * rsqrtf(bv[oh] + 1e-5f);
      v = cw[((oh * 8 + ih) * 3 + dr) * 3 + tap] * ah;
    }
    sA[tap][m][kk] = f2bf(v);
  }
  // Zero halo columns ci = 0, 1025, 1026.
  if (tid < 96) {
    int which = tid >> 5, g = tid & 31;
    int ci = (which == 0) ? 0 : 1024 + which;
    sC[ci * 34 + g] = 0;
  }
  // Stage S col-major: pairs of g rows -> u32 writes.
  for (int it = 0; it < 16; ++it) {
    int u = tid + it * 256;             // u = gp*256 + cseg
    int gp = u >> 8, cseg = u & 255;
    int g0 = gp * 2;
    int ih = g0 >> 2, rr0 = g0 & 3;
    int r0 = i0 - 1 + rr0, r1 = r0 + 1;
    int c0 = cseg * 4;
    u32 w0 = 0, w1 = 0;
    if (r0 >= 0 && r0 < 1024)
      w0 = *(const u32*)&S8[((size_t)(b * 8 + ih) << 20) + (size_t)r0 * 1024 + c0];
    if (r1 >= 0 && r1 < 1024)
      w1 = *(const u32*)&S8[((size_t)(b * 8 + ih) << 20) + (size_t)r1 * 1024 + c0];
    f32x2 lo0 = up2_lo(w0), hi0 = up2_hi(w0);
    f32x2 lo1 = up2_lo(w1), hi1 = up2_hi(w1);
    float v0[4] = {lo0.x, lo0.y, hi0.x, hi0.y};
    float v1[4] = {lo1.x, lo1.y, hi1.x, hi1.y};
#pragma unroll
    for (int cc = 0; cc < 4; ++cc)
      *(u32*)&sC[(size_t)(c0 + cc + 1) * 34 + g0] = cvtpk_bf16(v0[cc], v1[cc]);
  }
  __syncthreads();

  // A fragments (3 taps), per-lane constants.
  bf16x8 afr[3];
#pragma unroll
  for (int tap = 0; tap < 3; ++tap)
    afr[tap] = *(bf16x8*)&sA[tap][l15][l4 * 8];
  float bias2[4];
#pragma unroll
  for (int r = 0; r < 4; ++r) {
    int m = l4 * 4 + r, oh = m & 7;
    float ah = bg[oh] * rsqrtf(bv[oh] + 1e-5f);
    bias2[r] = cb[oh] * ah + bb[oh] - bm[oh] * ah;
  }
  float dsum[4] = {0.f, 0.f, 0.f, 0.f};

  const int jw = wid * 256;
  for (int t = 0; t < 16; ++t) {
    int j = jw + t * 16;
    f32x4 acc = {0.f, 0.f, 0.f, 0.f};
#pragma unroll
    for (int tap = 0; tap < 3; ++tap) {
      bf16x8 bfrag = *(bf16x8*)&sC[(size_t)(j + l15 + tap) * 34 + l4 * 8];
      acc = __builtin_amdgcn_mfma_f32_16x16x32_bf16(afr[tap], bfrag, acc, 0, 0, 0);
    }
#pragma unroll
    for (int r = 0; r < 4; ++r) {
      int m = l4 * 4 + r;
      int p = m >> 3, oh = m & 7;
      float tt = acc[r] + bias2[r];
      float sg = 1.f / (1.f + __expf(-tt));
      float e = __expf(sg);
      unsigned char q8 = f2fp8(e);
      P8[((size_t)(b * 8 + oh) << 20) + ((size_t)(i0 + p) << 10) + j + l15] = q8;
      dsum[r] += up2_lo((u32)q8).x;  // quantized numerator for exact norm
    }
  }
#pragma unroll
  for (int r = 0; r < 4; ++r) {
#pragma unroll
    for (int msk = 8; msk >= 1; msk >>= 1) dsum[r] += __shfl_xor(dsum[r], msk);
  }
  if (l15 == 0) {
#pragma unroll
    for (int r = 0; r < 4; ++r) sRedD[wid][l4 * 4 + r] = dsum[r];
  }
  __syncthreads();
  if (tid < 16) {
    int p = tid >> 3, oh = tid & 7;
    D[((size_t)(b * 8 + oh) << 10) + i0 + p] =
        sRedD[0][tid] + sRedD[1][tid] + sRedD[2][tid] + sRedD[3][tid];
  }
}

// ---------- Kernel 4: Z = (P @ V) / D per (b,h), fp8 MFMA ----------
__global__ __launch_bounds__(256) void k_av(const unsigned char* __restrict__ P8,
                                            const u16* __restrict__ V,
                                            const float* __restrict__ D,
                                            u16* __restrict__ Z) {
  const int bh = blockIdx.y, m0 = blockIdx.x * 128;
  const int b = bh >> 3, h = bh & 7;
  __shared__ __align__(16) unsigned char sA8[128 * 64];
  __shared__ __align__(16) unsigned char sVt[64 * 64];
  const int tid = threadIdx.x, lane = tid & 63, wid = tid >> 6;
  const int wr = wid >> 1, wc = wid & 1, l15 = lane & 15, l4 = lane >> 4;
  f32x4 acc[4][2] = {};
  for (int k0 = 0; k0 < 1024; k0 += 64) {
    __syncthreads();
    {  // stage A (P fp8), swizzled
      int row = tid >> 1, c0 = (tid & 1) * 32;
      const unsigned char* src =
          &P8[((size_t)bh << 20) + (size_t)(m0 + row) * 1024 + k0 + c0];
      uint4 a0 = *(const uint4*)src, a1 = *(const uint4*)(src + 16);
      u64 ul[4];
      ul[0] = (u64)a0.x | ((u64)a0.y << 32);
      ul[1] = (u64)a0.z | ((u64)a0.w << 32);
      ul[2] = (u64)a1.x | ((u64)a1.y << 32);
      ul[3] = (u64)a1.z | ((u64)a1.w << 32);
      int xr = row & 7, gb = c0 >> 3;
#pragma unroll
      for (int t = 0; t < 4; ++t)
        *(u64*)&sA8[row * 64 + ((gb + t) ^ xr) * 8] = ul[t];
    }
    {  // stage V^T as fp8, swizzled
      int j = tid >> 2, d0 = (tid & 3) * 16;
      const u16* src = &V[((size_t)bh << 16) + (size_t)(k0 + j) * 64 + d0];
      uint4 v0 = *(const uint4*)src, v1 = *(const uint4*)(src + 16);
      u32 wv[8] = {v0.x, v0.y, v0.z, v0.w, v1.x, v1.y, v1.z, v1.w};
#pragma unroll
      for (int t = 0; t < 8; ++t) {
        u32 p = (u32)__builtin_amdgcn_cvt_pk_fp8_f32(bflo(wv[t]), bfhi(wv[t]), 0, false);
        int da = d0 + t * 2, db = da + 1;
        sVt[da * 64 + (((j >> 3) ^ (da & 7)) << 3) + (j & 7)] = (unsigned char)(p & 0xff);
        sVt[db * 64 + (((j >> 3) ^ (db & 7)) << 3) + (j & 7)] = (unsigned char)((p >> 8) & 0xff);
      }
    }
    __syncthreads();
    long bfr[2][2];
#pragma unroll
    for (int nr = 0; nr < 2; ++nr) {
      int row = wc * 32 + nr * 16 + l15;
#pragma unroll
      for (int ks = 0; ks < 2; ++ks)
        bfr[nr][ks] = *(long*)&sVt[row * 64 + (((ks * 4 + l4) ^ (row & 7)) << 3)];
    }
#pragma unroll
    for (int mr = 0; mr < 4; ++mr) {
      int row = wr * 64 + mr * 16 + l15;
      long afr[2];
#pragma unroll
      for (int ks = 0; ks < 2; ++ks)
        afr[ks] = *(long*)&sA8[row * 64 + (((ks * 4 + l4) ^ (row & 7)) << 3)];
#pragma unroll
      for (int nr = 0; nr < 2; ++nr)
#pragma unroll
        for (int ks = 0; ks < 2; ++ks)
          acc[mr][nr] = __builtin_amdgcn_mfma_f32_16x16x32_fp8_fp8(afr[ks], bfr[nr][ks],
                                                                   acc[mr][nr], 0, 0, 0);
    }
  }
#pragma unroll
  for (int mr = 0; mr < 4; ++mr) {
    int mbase = m0 + wr * 64 + mr * 16 + l4 * 4;
    float dv[4];
#pragma unroll
    for (int r = 0; r < 4; ++r) dv[r] = 1.f / D[((size_t)bh << 10) + mbase + r];
#pragma unroll
    for (int nr = 0; nr < 2; ++nr) {
      int d = wc * 32 + nr * 16 + l15;
#pragma unroll
      for (int r = 0; r < 4; ++r)
        Z[((size_t)(b * 1024 + mbase + r)) * 512 + h * 64 + d] =
            f2bf(acc[mr][nr][r] * dv[r]);
    }
  }
}

// ---------- Kernel 5: out = Z @ W^T + b + x, bf16 MFMA. M=8192,N=512,K=512 ----------
__global__ __launch_bounds__(256) void k_proj(const u16* __restrict__ Z,
                                              const float* __restrict__ w,
                                              const float* __restrict__ bias,
                                              const float* __restrict__ xin,
                                              float* __restrict__ out) {
  __shared__ __align__(16) u16 sA[128 * 64];
  __shared__ __align__(16) u16 sB[128 * 64];
  const int tid = threadIdx.x;
  const int m0 = blockIdx.x * 128, n0 = blockIdx.y * 128;
  const int lane = tid & 63, wid = tid >> 6;
  const int wr = wid >> 1, wc = wid & 1;
  const int l15 = lane & 15, l4 = lane >> 4;
  const int row = tid >> 1, half = tid & 1, xr = row & 7;
  f32x4 acc[4][4] = {};
  for (int k0 = 0; k0 < 512; k0 += 64) {
    __syncthreads();
    {
      const u16* gz = &Z[(size_t)(m0 + row) * 512 + k0 + half * 32];
      const float* gb = &w[(size_t)(n0 + row) * 512 + k0 + half * 32];
#pragma unroll
      for (int q = 0; q < 4; ++q) {
        int gp = (half * 4 + q) ^ xr;
        *(uint4*)&sA[row * 64 + gp * 8] = *(const uint4*)&gz[q * 8];
        float4 b0 = *(const float4*)&gb[q * 8];
        float4 b1 = *(const float4*)&gb[q * 8 + 4];
        uint4 pb;
        pb.x = cvtpk_bf16(b0.x, b0.y); pb.y = cvtpk_bf16(b0.z, b0.w);
        pb.z = cvtpk_bf16(b1.x, b1.y); pb.w = cvtpk_bf16(b1.z, b1.w);
        *(uint4*)&sB[row * 64 + gp * 8] = pb;
      }
    }
    __syncthreads();
#pragma unroll
    for (int ks = 0; ks < 2; ++ks) {
      bf16x8 af[4], bfr[4];
#pragma unroll
      for (int mr = 0; mr < 4; ++mr) {
        int rr = wr * 64 + mr * 16 + l15;
        af[mr] = *(bf16x8*)&sA[rr * 64 + ((ks * 4 + l4) ^ (rr & 7)) * 8];
      }
#pragma unroll
      for (int nr = 0; nr < 4; ++nr) {
        int rr = wc * 64 + nr * 16 + l15;
        bfr[nr] = *(bf16x8*)&sB[rr * 64 + ((ks * 4 + l4) ^ (rr & 7)) * 8];
      }
#pragma unroll
      for (int mr = 0; mr < 4; ++mr)
#pragma unroll
        for (int nr = 0; nr < 4; ++nr)
          acc[mr][nr] = __builtin_amdgcn_mfma_f32_16x16x32_bf16(af[mr], bfr[nr],
                                                                acc[mr][nr], 0, 0, 0);
    }
  }
#pragma unroll
  for (int nr = 0; nr < 4; ++nr) {
    int nn = n0 + wc * 64 + nr * 16 + l15;
    float bv2 = bias[nn];
#pragma unroll
    for (int mr = 0; mr < 4; ++mr) {
      int mb = m0 + wr * 64 + mr * 16 + l4 * 4;
#pragma unroll
      for (int r = 0; r < 4; ++r) {
        size_t o = (size_t)(mb + r) * 512 + nn;
        out[o] = acc[mr][nr][r] + bv2 + xin[o];
      }
    }
  }
}

extern "C" void kernel_launch(void* const* d_in, const int* in_sizes, int n_in,
                              void* d_out, int out_size, void* d_ws, size_t ws_size,
                              hipStream_t stream) {
  const size_t need = 160ull << 20;
  if (ws_size < need) return;  // clean diagnostic failure instead of GPU fault

  const float* x      = (const float*)d_in[0];
  const float* qkv_w  = (const float*)d_in[1];
  const float* proj_w = (const float*)d_in[2];
  const float* proj_b = (const float*)d_in[3];
  const float* conv_w = (const float*)d_in[4];
  const float* conv_b = (const float*)d_in[5];
  const float* bn_g   = (const float*)d_in[6];
  const float* bn_b   = (const float*)d_in[7];
  const float* bn_m   = (const float*)d_in[8];
  const float* bn_v   = (const float*)d_in[9];
  float* out = (float*)d_out;

  char* W = (char*)d_ws;
  u16* Wq = (u16*)W;                       // Q bf16 8MB; dead after k_qk
  float* Dbuf = (float*)W;                 // D f32 256KB, overlays Q region
  u16* Wk = (u16*)(W + (8ull << 20));
  u16* Wv = (u16*)(W + (16ull << 20));
  u16* Wz = (u16*)(W + (24ull << 20));
  unsigned char* S8 = (unsigned char*)(W + (32ull << 20));  // 64MB
  unsigned char* P8 = (unsigned char*)(W + (96ull << 20));  // 64MB

  k_qkv<<<dim3(64, 12), 256, 0, stream>>>(x, qkv_w, Wq, Wk, Wv);
  k_qk<<<dim3(8, 8, 64), 256, 0, stream>>>(Wq, Wk, S8);
  k_conv<<<dim3(4096), 256, 0, stream>>>(S8, P8, Dbuf, conv_w, conv_b, bn_g, bn_b,
                                         bn_m, bn_v);
  k_av<<<dim3(8, 64), 256, 0, stream>>>(P8, Wv, Dbuf, Wz);
  k_proj<<<dim3(64, 4), 256, 0, stream>>>(Wz, proj_w, proj_b, x, out);
}

// Round 9
// 219.150 us; speedup vs baseline: 8.8635x; 1.1941x over previous
//
#include <hip/hip_runtime.h>

// GuidedAttention on MI355X, round 9: k_conv now an all-fp8 MFMA GEMM.
// B = raw S fp8 bytes staged col-major (4x4 byte-transpose, conflict-free),
// A = conv weights x BN scale quantized to fp8. No bf16 decode anywhere.
// Other kernels unchanged from validated round-8 build.
// b=8, n=1024, c=512, H=8, hd=64.
// ws layout (160 MB): [Q bf16 8MB | D f32 256KB overlaid after k_qk]
//                     [K bf16 8MB][V bf16 8MB][Z bf16 8MB]
//                     [S fp8 64MB][P fp8 64MB]

#define DINL __device__ __forceinline__
typedef unsigned short u16;
typedef unsigned int u32;
typedef unsigned long long u64;
typedef short bf16x8 __attribute__((ext_vector_type(8)));
typedef float f32x4 __attribute__((ext_vector_type(4)));
typedef float f32x2 __attribute__((ext_vector_type(2)));

DINL u16 f2bf(float f) {
  u32 u = __float_as_uint(f);
  u += 0x7fffu + ((u >> 16) & 1u);
  return (u16)(u >> 16);
}
DINL float bflo(u32 u) { return __uint_as_float(u << 16); }
DINL float bfhi(u32 u) { return __uint_as_float(u & 0xffff0000u); }
DINL u32 cvtpk_bf16(float lo, float hi) {
  u32 r;
  asm("v_cvt_pk_bf16_f32 %0, %1, %2" : "=v"(r) : "v"(lo), "v"(hi));
  return r;
}
DINL f32x2 up2_lo(u32 w) { return __builtin_amdgcn_cvt_pk_f32_fp8((int)w, false); }
DINL unsigned char f2fp8(float v) {
  return (unsigned char)((u32)__builtin_amdgcn_cvt_pk_fp8_f32(v, v, 0, false) & 0xffu);
}

// ---------- Kernel 1: QKV proj, bf16 MFMA. M=8192, N=1536, K=512 ----------
__global__ __launch_bounds__(256) void k_qkv(const float* __restrict__ x,
                                             const float* __restrict__ w,
                                             u16* __restrict__ Q,
                                             u16* __restrict__ K,
                                             u16* __restrict__ V) {
  __shared__ __align__(16) u16 sA[128 * 64];
  __shared__ __align__(16) u16 sB[128 * 64];
  const int tid = threadIdx.x;
  const int m0 = blockIdx.x * 128, n0 = blockIdx.y * 128;
  const int lane = tid & 63, wid = tid >> 6;
  const int wr = wid >> 1, wc = wid & 1;
  const int l15 = lane & 15, l4 = lane >> 4;
  const int row = tid >> 1, half = tid & 1, xr = row & 7;
  f32x4 acc[4][4] = {};
  for (int k0 = 0; k0 < 512; k0 += 64) {
    __syncthreads();
    {
      const float* ga = &x[(size_t)(m0 + row) * 512 + k0 + half * 32];
      const float* gb = &w[(size_t)(n0 + row) * 512 + k0 + half * 32];
#pragma unroll
      for (int q = 0; q < 4; ++q) {
        int gp = (half * 4 + q) ^ xr;
        float4 a0 = *(const float4*)&ga[q * 8];
        float4 a1 = *(const float4*)&ga[q * 8 + 4];
        uint4 pa;
        pa.x = cvtpk_bf16(a0.x, a0.y); pa.y = cvtpk_bf16(a0.z, a0.w);
        pa.z = cvtpk_bf16(a1.x, a1.y); pa.w = cvtpk_bf16(a1.z, a1.w);
        *(uint4*)&sA[row * 64 + gp * 8] = pa;
        float4 b0 = *(const float4*)&gb[q * 8];
        float4 b1 = *(const float4*)&gb[q * 8 + 4];
        uint4 pb;
        pb.x = cvtpk_bf16(b0.x, b0.y); pb.y = cvtpk_bf16(b0.z, b0.w);
        pb.z = cvtpk_bf16(b1.x, b1.y); pb.w = cvtpk_bf16(b1.z, b1.w);
        *(uint4*)&sB[row * 64 + gp * 8] = pb;
      }
    }
    __syncthreads();
#pragma unroll
    for (int ks = 0; ks < 2; ++ks) {
      bf16x8 af[4], bfr[4];
#pragma unroll
      for (int mr = 0; mr < 4; ++mr) {
        int rr = wr * 64 + mr * 16 + l15;
        af[mr] = *(bf16x8*)&sA[rr * 64 + ((ks * 4 + l4) ^ (rr & 7)) * 8];
      }
#pragma unroll
      for (int nr = 0; nr < 4; ++nr) {
        int rr = wc * 64 + nr * 16 + l15;
        bfr[nr] = *(bf16x8*)&sB[rr * 64 + ((ks * 4 + l4) ^ (rr & 7)) * 8];
      }
#pragma unroll
      for (int mr = 0; mr < 4; ++mr)
#pragma unroll
        for (int nr = 0; nr < 4; ++nr)
          acc[mr][nr] = __builtin_amdgcn_mfma_f32_16x16x32_bf16(af[mr], bfr[nr],
                                                                acc[mr][nr], 0, 0, 0);
    }
  }
#pragma unroll
  for (int nr = 0; nr < 4; ++nr) {
    int nn = n0 + wc * 64 + nr * 16 + l15;
    int which = nn >> 9, co = nn & 511;
    int head = co >> 6, d = co & 63;
    u16* dst = (which == 0) ? Q : (which == 1) ? K : V;
    float sc = (which == 0) ? 0.125f : 1.f;
#pragma unroll
    for (int mr = 0; mr < 4; ++mr) {
      int mb = m0 + wr * 64 + mr * 16 + l4 * 4;
#pragma unroll
      for (int r = 0; r < 4; ++r) {
        int m = mb + r;
        int bb = m >> 10, ii = m & 1023;
        dst[((((size_t)bb * 8 + head) << 10) + ii) * 64 + d] =
            f2bf(acc[mr][nr][r] * sc);
      }
    }
  }
}

// ---------- Kernel 2: S = Q @ K^T per (b,h), bf16 MFMA, out fp8 ----------
__global__ __launch_bounds__(256) void k_qk(const u16* __restrict__ Q,
                                            const u16* __restrict__ Kp,
                                            unsigned char* __restrict__ S8) {
  const int bh = blockIdx.z;
  const u16* Qb = Q + (size_t)bh * 65536;
  const u16* Kb = Kp + (size_t)bh * 65536;
  __shared__ __align__(16) u16 sQ[128 * 64];
  __shared__ __align__(16) u16 sK[128 * 64];
  const int tid = threadIdx.x;
  const int m0 = blockIdx.x * 128, n0 = blockIdx.y * 128;
  {
    int row = tid >> 1, half = tid & 1;
    const u16* gq = &Qb[(size_t)(m0 + row) * 64 + half * 32];
    const u16* gk = &Kb[(size_t)(n0 + row) * 64 + half * 32];
    int xr = row & 7;
#pragma unroll
    for (int q = 0; q < 4; ++q) {
      int gp = (half * 4 + q) ^ xr;
      *(uint4*)&sQ[row * 64 + gp * 8] = *(const uint4*)&gq[q * 8];
      *(uint4*)&sK[row * 64 + gp * 8] = *(const uint4*)&gk[q * 8];
    }
  }
  __syncthreads();
  const int lane = tid & 63, wid = tid >> 6;
  const int wr = wid >> 1, wc = wid & 1;
  const int l15 = lane & 15, l4 = lane >> 4;
  f32x4 acc[4][4] = {};
  bf16x8 af[4][2], bf[4][2];
#pragma unroll
  for (int mr = 0; mr < 4; ++mr) {
    int row = wr * 64 + mr * 16 + l15;
#pragma unroll
    for (int ks = 0; ks < 2; ++ks)
      af[mr][ks] = *(bf16x8*)&sQ[row * 64 + ((ks * 4 + l4) ^ (row & 7)) * 8];
  }
#pragma unroll
  for (int nr = 0; nr < 4; ++nr) {
    int row = wc * 64 + nr * 16 + l15;
#pragma unroll
    for (int ks = 0; ks < 2; ++ks)
      bf[nr][ks] = *(bf16x8*)&sK[row * 64 + ((ks * 4 + l4) ^ (row & 7)) * 8];
  }
#pragma unroll
  for (int mr = 0; mr < 4; ++mr)
#pragma unroll
    for (int nr = 0; nr < 4; ++nr)
#pragma unroll
      for (int ks = 0; ks < 2; ++ks)
        acc[mr][nr] = __builtin_amdgcn_mfma_f32_16x16x32_bf16(af[mr][ks], bf[nr][ks],
                                                              acc[mr][nr], 0, 0, 0);
  __syncthreads();
  unsigned char* t8 = (unsigned char*)sQ;  // reuse 16KB as fp8 [128][128]
#pragma unroll
  for (int mr = 0; mr < 4; ++mr) {
    int mloc = wr * 64 + mr * 16 + l4 * 4;
#pragma unroll
    for (int nr = 0; nr < 4; ++nr) {
      int nloc = wc * 64 + nr * 16 + l15;
#pragma unroll
      for (int r = 0; r < 4; ++r)
        t8[(mloc + r) * 128 + nloc] = f2fp8(acc[mr][nr][r]);
    }
  }
  __syncthreads();
  {
    int row = tid >> 1, c0 = (tid & 1) * 64;
    unsigned char* dst = &S8[((size_t)bh << 20) + (size_t)(m0 + row) * 1024 + n0 + c0];
#pragma unroll
    for (int q = 0; q < 4; ++q)
      *(uint4*)&dst[q * 16] = *(uint4*)&t8[row * 128 + c0 + q * 16];
  }
}

// ---------- Kernel 3: conv3x3(heads)+BN+sigmoid+exp, all-fp8 MFMA GEMM ----------
// Block per (b, row-pair). M=16 = (p in {0,1}) x (oh in 0..7).
// Per tap: one fp8 MFMA with K=32 (k = ih*4 + rr, rr = staged row).
// A[m][k] = fp8(ah[oh] * cw[oh][ih][rr-p][tap])  (0 if rr-p not in [0,3)).
// B[k][j] = S8[b,ih,i0-1+rr, j+tap-1] staged col-major (raw bytes, no decode).
__global__ __launch_bounds__(256) void k_conv(
    const unsigned char* __restrict__ S8, unsigned char* __restrict__ P8,
    float* __restrict__ D, const float* __restrict__ cw,
    const float* __restrict__ cb, const float* __restrict__ bg,
    const float* __restrict__ bb, const float* __restrict__ bm,
    const float* __restrict__ bv) {
  const int b = blockIdx.x >> 9, ip = blockIdx.x & 511;
  const int i0 = ip * 2;
  __shared__ __align__(16) unsigned char sC[1026 * 40];  // [ci][k], 40B pitch, 41KB
  __shared__ __align__(8) unsigned char sA[3][16][40];   // A-frags per tap, fp8
  __shared__ float sRedD[4][16];
  const int tid = threadIdx.x;
  const int lane = tid & 63, wid = tid >> 6;
  const int l15 = lane & 15, l4 = lane >> 4;

  // Build A fp8 (weights folded with BN scale). 1536 entries.
  for (int u = tid; u < 1536; u += 256) {
    int tap = u >> 9, rem = u & 511;
    int m = rem >> 5, kk = rem & 31;
    int p = m >> 3, oh = m & 7;
    int ih = kk >> 2, rr = kk & 3;
    int dr = rr - p;
    float v = 0.f;
    if (dr >= 0 && dr < 3) {
      float ah = bg[oh] * rsqrtf(bv[oh] + 1e-5f);
      v = cw[((oh * 8 + ih) * 3 + dr) * 3 + tap] * ah;
    }
    sA[tap][m][kk] = f2fp8(v);
  }
  // Zero halo cols ci=0 (input col -1) and ci=1025 (input col 1024).
  if (tid < 20) {
    int c = (tid < 10) ? 0 : 1025;
    ((u32*)&sC[c * 40])[tid % 10] = 0;
  }
  // Stage S col-major via 4x4 byte transpose. Lanes 0-31 of each half-wave
  // share one ih -> coalesced 128B loads; writes walk consecutive ci at a
  // 10-word pitch -> conflict-free.
  {
    const int ihs = tid >> 5;  // 0..7
    const int lc = tid & 31;
    const unsigned char* Sb = S8 + (((size_t)(b * 8 + ihs)) << 20);
    for (int it = 0; it < 8; ++it) {
      int c0 = (lc + it * 32) * 4;
      u32 w[4];
#pragma unroll
      for (int rr = 0; rr < 4; ++rr) {
        int r = i0 - 1 + rr;
        w[rr] = (r >= 0 && r < 1024) ? *(const u32*)&Sb[(size_t)r * 1024 + c0] : 0u;
      }
#pragma unroll
      for (int cc = 0; cc < 4; ++cc) {
        u32 v = ((w[0] >> (8 * cc)) & 0xffu) | (((w[1] >> (8 * cc)) & 0xffu) << 8) |
                (((w[2] >> (8 * cc)) & 0xffu) << 16) |
                (((w[3] >> (8 * cc)) & 0xffu) << 24);
        *(u32*)&sC[(c0 + cc + 1) * 40 + ihs * 4] = v;
      }
    }
  }
  __syncthreads();

  // A fragments (3 taps) + per-lane epilogue constants.
  long afr[3];
#pragma unroll
  for (int tap = 0; tap < 3; ++tap)
    afr[tap] = *(long*)&sA[tap][l15][l4 * 8];
  float bias2[4];
#pragma unroll
  for (int r = 0; r < 4; ++r) {
    int m = l4 * 4 + r, oh = m & 7;
    float ah = bg[oh] * rsqrtf(bv[oh] + 1e-5f);
    bias2[r] = cb[oh] * ah + bb[oh] - bm[oh] * ah;
  }
  float dsum[4] = {0.f, 0.f, 0.f, 0.f};

  const int jw = wid * 256;
  for (int t = 0; t < 16; ++t) {
    int j = jw + t * 16;
    f32x4 acc = {0.f, 0.f, 0.f, 0.f};
#pragma unroll
    for (int tap = 0; tap < 3; ++tap) {
      long bfrag = *(long*)&sC[(size_t)(j + l15 + tap) * 40 + l4 * 8];
      acc = __builtin_amdgcn_mfma_f32_16x16x32_fp8_fp8(afr[tap], bfrag, acc, 0, 0, 0);
    }
#pragma unroll
    for (int r = 0; r < 4; ++r) {
      int m = l4 * 4 + r;
      int p = m >> 3, oh = m & 7;
      float tt = acc[r] + bias2[r];
      float sg = 1.f / (1.f + __expf(-tt));
      float e = __expf(sg);
      unsigned char q8 = f2fp8(e);
      P8[((size_t)(b * 8 + oh) << 20) + ((size_t)(i0 + p) << 10) + j + l15] = q8;
      dsum[r] += up2_lo((u32)q8).x;  // quantized numerator for exact norm
    }
  }
#pragma unroll
  for (int r = 0; r < 4; ++r) {
#pragma unroll
    for (int msk = 8; msk >= 1; msk >>= 1) dsum[r] += __shfl_xor(dsum[r], msk);
  }
  if (l15 == 0) {
#pragma unroll
    for (int r = 0; r < 4; ++r) sRedD[wid][l4 * 4 + r] = dsum[r];
  }
  __syncthreads();
  if (tid < 16) {
    int p = tid >> 3, oh = tid & 7;
    D[((size_t)(b * 8 + oh) << 10) + i0 + p] =
        sRedD[0][tid] + sRedD[1][tid] + sRedD[2][tid] + sRedD[3][tid];
  }
}

// ---------- Kernel 4: Z = (P @ V) / D per (b,h), fp8 MFMA ----------
__global__ __launch_bounds__(256) void k_av(const unsigned char* __restrict__ P8,
                                            const u16* __restrict__ V,
                                            const float* __restrict__ D,
                                            u16* __restrict__ Z) {
  const int bh = blockIdx.y, m0 = blockIdx.x * 128;
  const int b = bh >> 3, h = bh & 7;
  __shared__ __align__(16) unsigned char sA8[128 * 64];
  __shared__ __align__(16) unsigned char sVt[64 * 64];
  const int tid = threadIdx.x, lane = tid & 63, wid = tid >> 6;
  const int wr = wid >> 1, wc = wid & 1, l15 = lane & 15, l4 = lane >> 4;
  f32x4 acc[4][2] = {};
  for (int k0 = 0; k0 < 1024; k0 += 64) {
    __syncthreads();
    {  // stage A (P fp8), swizzled
      int row = tid >> 1, c0 = (tid & 1) * 32;
      const unsigned char* src =
          &P8[((size_t)bh << 20) + (size_t)(m0 + row) * 1024 + k0 + c0];
      uint4 a0 = *(const uint4*)src, a1 = *(const uint4*)(src + 16);
      u64 ul[4];
      ul[0] = (u64)a0.x | ((u64)a0.y << 32);
      ul[1] = (u64)a0.z | ((u64)a0.w << 32);
      ul[2] = (u64)a1.x | ((u64)a1.y << 32);
      ul[3] = (u64)a1.z | ((u64)a1.w << 32);
      int xr = row & 7, gb = c0 >> 3;
#pragma unroll
      for (int t = 0; t < 4; ++t)
        *(u64*)&sA8[row * 64 + ((gb + t) ^ xr) * 8] = ul[t];
    }
    {  // stage V^T as fp8, swizzled
      int j = tid >> 2, d0 = (tid & 3) * 16;
      const u16* src = &V[((size_t)bh << 16) + (size_t)(k0 + j) * 64 + d0];
      uint4 v0 = *(const uint4*)src, v1 = *(const uint4*)(src + 16);
      u32 wv[8] = {v0.x, v0.y, v0.z, v0.w, v1.x, v1.y, v1.z, v1.w};
#pragma unroll
      for (int t = 0; t < 8; ++t) {
        u32 p = (u32)__builtin_amdgcn_cvt_pk_fp8_f32(bflo(wv[t]), bfhi(wv[t]), 0, false);
        int da = d0 + t * 2, db = da + 1;
        sVt[da * 64 + (((j >> 3) ^ (da & 7)) << 3) + (j & 7)] = (unsigned char)(p & 0xff);
        sVt[db * 64 + (((j >> 3) ^ (db & 7)) << 3) + (j & 7)] = (unsigned char)((p >> 8) & 0xff);
      }
    }
    __syncthreads();
    long bfr[2][2];
#pragma unroll
    for (int nr = 0; nr < 2; ++nr) {
      int row = wc * 32 + nr * 16 + l15;
#pragma unroll
      for (int ks = 0; ks < 2; ++ks)
        bfr[nr][ks] = *(long*)&sVt[row * 64 + (((ks * 4 + l4) ^ (row & 7)) << 3)];
    }
#pragma unroll
    for (int mr = 0; mr < 4; ++mr) {
      int row = wr * 64 + mr * 16 + l15;
      long afr[2];
#pragma unroll
      for (int ks = 0; ks < 2; ++ks)
        afr[ks] = *(long*)&sA8[row * 64 + (((ks * 4 + l4) ^ (row & 7)) << 3)];
#pragma unroll
      for (int nr = 0; nr < 2; ++nr)
#pragma unroll
        for (int ks = 0; ks < 2; ++ks)
          acc[mr][nr] = __builtin_amdgcn_mfma_f32_16x16x32_fp8_fp8(afr[ks], bfr[nr][ks],
                                                                   acc[mr][nr], 0, 0, 0);
    }
  }
#pragma unroll
  for (int mr = 0; mr < 4; ++mr) {
    int mbase = m0 + wr * 64 + mr * 16 + l4 * 4;
    float dv[4];
#pragma unroll
    for (int r = 0; r < 4; ++r) dv[r] = 1.f / D[((size_t)bh << 10) + mbase + r];
#pragma unroll
    for (int nr = 0; nr < 2; ++nr) {
      int d = wc * 32 + nr * 16 + l15;
#pragma unroll
      for (int r = 0; r < 4; ++r)
        Z[((size_t)(b * 1024 + mbase + r)) * 512 + h * 64 + d] =
            f2bf(acc[mr][nr][r] * dv[r]);
    }
  }
}

// ---------- Kernel 5: out = Z @ W^T + b + x, bf16 MFMA. M=8192,N=512,K=512 ----------
__global__ __launch_bounds__(256) void k_proj(const u16* __restrict__ Z,
                                              const float* __restrict__ w,
                                              const float* __restrict__ bias,
                                              const float* __restrict__ xin,
                                              float* __restrict__ out) {
  __shared__ __align__(16) u16 sA[128 * 64];
  __shared__ __align__(16) u16 sB[128 * 64];
  const int tid = threadIdx.x;
  const int m0 = blockIdx.x * 128, n0 = blockIdx.y * 128;
  const int lane = tid & 63, wid = tid >> 6;
  const int wr = wid >> 1, wc = wid & 1;
  const int l15 = lane & 15, l4 = lane >> 4;
  const int row = tid >> 1, half = tid & 1, xr = row & 7;
  f32x4 acc[4][4] = {};
  for (int k0 = 0; k0 < 512; k0 += 64) {
    __syncthreads();
    {
      const u16* gz = &Z[(size_t)(m0 + row) * 512 + k0 + half * 32];
      const float* gb = &w[(size_t)(n0 + row) * 512 + k0 + half * 32];
#pragma unroll
      for (int q = 0; q < 4; ++q) {
        int gp = (half * 4 + q) ^ xr;
        *(uint4*)&sA[row * 64 + gp * 8] = *(const uint4*)&gz[q * 8];
        float4 b0 = *(const float4*)&gb[q * 8];
        float4 b1 = *(const float4*)&gb[q * 8 + 4];
        uint4 pb;
        pb.x = cvtpk_bf16(b0.x, b0.y); pb.y = cvtpk_bf16(b0.z, b0.w);
        pb.z = cvtpk_bf16(b1.x, b1.y); pb.w = cvtpk_bf16(b1.z, b1.w);
        *(uint4*)&sB[row * 64 + gp * 8] = pb;
      }
    }
    __syncthreads();
#pragma unroll
    for (int ks = 0; ks < 2; ++ks) {
      bf16x8 af[4], bfr[4];
#pragma unroll
      for (int mr = 0; mr < 4; ++mr) {
        int rr = wr * 64 + mr * 16 + l15;
        af[mr] = *(bf16x8*)&sA[rr * 64 + ((ks * 4 + l4) ^ (rr & 7)) * 8];
      }
#pragma unroll
      for (int nr = 0; nr < 4; ++nr) {
        int rr = wc * 64 + nr * 16 + l15;
        bfr[nr] = *(bf16x8*)&sB[rr * 64 + ((ks * 4 + l4) ^ (rr & 7)) * 8];
      }
#pragma unroll
      for (int mr = 0; mr < 4; ++mr)
#pragma unroll
        for (int nr = 0; nr < 4; ++nr)
          acc[mr][nr] = __builtin_amdgcn_mfma_f32_16x16x32_bf16(af[mr], bfr[nr],
                                                                acc[mr][nr], 0, 0, 0);
    }
  }
#pragma unroll
  for (int nr = 0; nr < 4; ++nr) {
    int nn = n0 + wc * 64 + nr * 16 + l15;
    float bv2 = bias[nn];
#pragma unroll
    for (int mr = 0; mr < 4; ++mr) {
      int mb = m0 + wr * 64 + mr * 16 + l4 * 4;
#pragma unroll
      for (int r = 0; r < 4; ++r) {
        size_t o = (size_t)(mb + r) * 512 + nn;
        out[o] = acc[mr][nr][r] + bv2 + xin[o];
      }
    }
  }
}

extern "C" void kernel_launch(void* const* d_in, const int* in_sizes, int n_in,
                              void* d_out, int out_size, void* d_ws, size_t ws_size,
                              hipStream_t stream) {
  const size_t need = 160ull << 20;
  if (ws_size < need) return;  // clean diagnostic failure instead of GPU fault

  const float* x      = (const float*)d_in[0];
  const float* qkv_w  = (const float*)d_in[1];
  const float* proj_w = (const float*)d_in[2];
  const float* proj_b = (const float*)d_in[3];
  const float* conv_w = (const float*)d_in[4];
  const float* conv_b = (const float*)d_in[5];
  const float* bn_g   = (const float*)d_in[6];
  const float* bn_b   = (const float*)d_in[7];
  const float* bn_m   = (const float*)d_in[8];
  const float* bn_v   = (const float*)d_in[9];
  float* out = (float*)d_out;

  char* W = (char*)d_ws;
  u16* Wq = (u16*)W;                       // Q bf16 8MB; dead after k_qk
  float* Dbuf = (float*)W;                 // D f32 256KB, overlays Q region
  u16* Wk = (u16*)(W + (8ull << 20));
  u16* Wv = (u16*)(W + (16ull << 20));
  u16* Wz = (u16*)(W + (24ull << 20));
  unsigned char* S8 = (unsigned char*)(W + (32ull << 20));  // 64MB
  unsigned char* P8 = (unsigned char*)(W + (96ull << 20));  // 64MB

  k_qkv<<<dim3(64, 12), 256, 0, stream>>>(x, qkv_w, Wq, Wk, Wv);
  k_qk<<<dim3(8, 8, 64), 256, 0, stream>>>(Wq, Wk, S8);
  k_conv<<<dim3(4096), 256, 0, stream>>>(S8, P8, Dbuf, conv_w, conv_b, bn_g, bn_b,
                                         bn_m, bn_v);
  k_av<<<dim3(8, 64), 256, 0, stream>>>(P8, Wv, Dbuf, Wz);
  k_proj<<<dim3(64, 4), 256, 0, stream>>>(Wz, proj_w, proj_b, x, out);
}